// Round 14
// baseline (6177.035 us; speedup 1.0000x reference)
//
#include <hip/hip_runtime.h>
#include <hip/hip_bf16.h>

// vGINMolEncoder: 5-layer GINE + virtual node, H=300, f32 in/out.
// Round 14: MLP 8 waves/block (512 thr), 1 row-tile per wave (was 4 waves x
// 2 rtiles). Same 32-row tile, same LDS (40,960B), same traffic; 2x resident
// waves (24/CU at 3 blocks) to hide L2 weight-load latency. Per-wave live set
// shrinks, so launch_bounds(512,4) (cap 128) cannot spill.
// Split-bf16 (hi+lo) MFMA, f32 accum.

#define HD 300
#define HD2 600
#define HDP 304   // padded pre row (shorts)
#define NLAYER 5
#define KS1 10   // 320/32
#define KS2 19   // 608/32
#define CT1P 40  // padded hidden col tiles (38 real)
#define CT2P 20  // padded out col tiles (19 real)
#define CAP 8
#define OVF_MAX 8192

typedef __attribute__((ext_vector_type(8))) short short8v;
typedef __attribute__((ext_vector_type(4))) short short4v;
typedef __attribute__((ext_vector_type(4))) float f32x4;

__device__ __forceinline__ short f2bf(float x) {  // RNE f32->bf16
  union { float f; unsigned u; } v; v.f = x;
  unsigned r = v.u + 0x7fffu + ((v.u >> 16) & 1u);
  return (short)(r >> 16);
}
__device__ __forceinline__ float bf2f(short h) {
  union { unsigned u; float f; } v; v.u = ((unsigned)(unsigned short)h) << 16;
  return v.f;
}

__device__ __forceinline__ void cvt8(f32x4 x0, f32x4 x1, short8v& fh, short8v& fl) {
#pragma unroll
  for (int j = 0; j < 4; ++j) { short hi = f2bf(x0[j]); fh[j] = hi; fl[j] = f2bf(x0[j] - bf2f(hi)); }
#pragma unroll
  for (int j = 0; j < 4; ++j) { short hi = f2bf(x1[j]); fh[4 + j] = hi; fl[4 + j] = f2bf(x1[j] - bf2f(hi)); }
}

// ---------- weight repack to hi/lo fragment order ----------
__global__ __launch_bounds__(256) void k_prep_wf(const float* __restrict__ W,
                                                 short* __restrict__ Whi,
                                                 short* __restrict__ Wlo,
                                                 int K, int C, int nks, int total) {
  int idx = blockIdx.x * 256 + threadIdx.x;
  if (idx >= total) return;
  int j = idx & 7, lane = (idx >> 3) & 63, t = idx >> 9;
  int ks = t % nks, ct = t / nks;
  int k = ks * 32 + (lane >> 4) * 8 + j;
  int c = ct * 16 + (lane & 15);
  float w = (k < K && c < C) ? W[(size_t)k * C + c] : 0.f;
  short hi = f2bf(w);
  Whi[idx] = hi;
  Wlo[idx] = f2bf(w - bf2f(hi));
}

// ---------- fused node MLP + BN-stats: 8 waves, 1 rtile/wave ----------
__global__ __launch_bounds__(512, 4) void k_mlp_mfma(
    const unsigned short* __restrict__ ph, const unsigned short* __restrict__ pl,
    const short* __restrict__ W1hi, const short* __restrict__ W1lo,
    const float* __restrict__ b1,
    const short* __restrict__ W2hi, const short* __restrict__ W2lo,
    const float* __restrict__ b2, float* __restrict__ out,
    float* __restrict__ stats, int N) {
  __shared__ __align__(16) short hidh[32 * 320];  // 20,480 B
  __shared__ __align__(16) short hidl[32 * 320];  // 20,480 B
  char* hbh = (char*)hidh;
  char* hbl = (char*)hidl;
  const int tid = threadIdx.x;
  const int lane = tid & 63, w = tid >> 6;
  const int rt = w & 1, cq = w >> 1;          // 2 row-tiles x 4 col-quarters
  const int li = lane & 15, g = lane >> 4;
  const int row0 = blockIdx.x * 32;
  const int lrow = rt * 16 + li;              // row within 32-row tile
  const size_t rb = (size_t)(row0 + lrow) * HDP;
  const int sw = (lrow & 7) << 4;

  f32x4 acc2[5];
#pragma unroll
  for (int t = 0; t < 5; ++t) acc2[t] = (f32x4){0.f, 0.f, 0.f, 0.f};

#pragma unroll 1
  for (int hf = 0; hf < 2; ++hf) {
    const int ct0 = hf * 20 + cq * 5;
    // ---- phase 1: 5 hidden ctiles for this wave's rtile ----
    f32x4 acc1[5];
#pragma unroll
    for (int t = 0; t < 5; ++t) acc1[t] = (f32x4){0.f, 0.f, 0.f, 0.f};
    for (int ks = 0; ks < KS1; ++ks) {
      int k0 = ks * 32 + g * 8;
      short8v ah = *(const short8v*)(ph + rb + k0);
      short8v al = *(const short8v*)(pl + rb + k0);
      const short8v* whp = (const short8v*)W1hi + ((size_t)ct0 * KS1 + ks) * 64 + lane;
      const short8v* wlp = (const short8v*)W1lo + ((size_t)ct0 * KS1 + ks) * 64 + lane;
#pragma unroll
      for (int ct = 0; ct < 5; ++ct) {
        short8v wh = whp[(size_t)ct * KS1 * 64];
        short8v wl = wlp[(size_t)ct * KS1 * 64];
        acc1[ct] = __builtin_amdgcn_mfma_f32_16x16x32_bf16(wh, ah, acc1[ct], 0, 0, 0);
        acc1[ct] = __builtin_amdgcn_mfma_f32_16x16x32_bf16(wh, al, acc1[ct], 0, 0, 0);
        acc1[ct] = __builtin_amdgcn_mfma_f32_16x16x32_bf16(wl, ah, acc1[ct], 0, 0, 0);
      }
    }
    if (hf) __syncthreads();  // prior half's phase-2 reads done
    // bias + relu -> split-bf16 LDS (convert once at write)
#pragma unroll
    for (int ct = 0; ct < 5; ++ct) {
      int ctile = ct0 + ct, cc = ctile - hf * 20;
      short4v vh, vl;
#pragma unroll
      for (int q = 0; q < 4; ++q) {
        int c = ctile * 16 + g * 4 + q;
        float bb = (c < HD2) ? b1[c] : 0.f;
        float v = fmaxf(acc1[ct][q] + bb, 0.f);
        short hi = f2bf(v);
        vh[q] = hi;
        vl[q] = f2bf(v - bf2f(hi));
      }
      int lin = lrow * 640 + cc * 32 + g * 8;
      *(short4v*)(hbh + (lin ^ sw)) = vh;
      *(short4v*)(hbl + (lin ^ sw)) = vl;
    }
    __syncthreads();
    // ---- phase 2 partial: ks of this half (pure ds_read + MFMA) ----
    const int nks2 = hf ? 9 : 10;
    for (int ksl = 0; ksl < nks2; ++ksl) {
      int ksg = hf * 10 + ksl;
      int lin = lrow * 640 + ksl * 64 + g * 16;
      short8v hh = *(const short8v*)(hbh + (lin ^ sw));
      short8v hl = *(const short8v*)(hbl + (lin ^ sw));
      const short8v* w2h = (const short8v*)W2hi + ((size_t)(cq * 5) * KS2 + ksg) * 64 + lane;
      const short8v* w2l = (const short8v*)W2lo + ((size_t)(cq * 5) * KS2 + ksg) * 64 + lane;
#pragma unroll
      for (int t = 0; t < 5; ++t) {
        short8v wh = w2h[(size_t)t * KS2 * 64];
        short8v wl = w2l[(size_t)t * KS2 * 64];
        acc2[t] = __builtin_amdgcn_mfma_f32_16x16x32_bf16(hh, wh, acc2[t], 0, 0, 0);
        acc2[t] = __builtin_amdgcn_mfma_f32_16x16x32_bf16(hl, wh, acc2[t], 0, 0, 0);
        acc2[t] = __builtin_amdgcn_mfma_f32_16x16x32_bf16(hh, wl, acc2[t], 0, 0, 0);
      }
    }
  }
  // epilogue: bias, store, fused column stats (this wave's 16 rows)
#pragma unroll
  for (int t = 0; t < 5; ++t) {
    int c2 = (cq * 5 + t) * 16 + li;
    if (c2 < HD) {
      float bb = b2[c2];
      float s = 0.f, sq = 0.f;
#pragma unroll
      for (int q = 0; q < 4; ++q) {
        int gr = row0 + rt * 16 + g * 4 + q;
        if (gr < N) {
          float val = acc2[t][q] + bb;
          out[(size_t)gr * HD + c2] = val;
          s += val;
          sq += val * val;
        }
      }
      s += __shfl_xor(s, 16);  s += __shfl_xor(s, 32);
      sq += __shfl_xor(sq, 16); sq += __shfl_xor(sq, 32);
      if (g == 0) {
        unsafeAtomicAdd(&stats[c2], s);
        unsafeAtomicAdd(&stats[HD + c2], sq);
      }
    }
  }
}

// ---------- generic split-bf16 MFMA GEMM for VN MLP ----------
// BNIN: apply BN(bnst,invM)+relu to A inline.  STATS: fused column stats out.
template <int NKS, int NCTQ, bool BNIN, bool STATS>
__global__ __launch_bounds__(512, 2) void k_gemm_mfma(
    const float* __restrict__ A, const float* __restrict__ A2,
    const float* __restrict__ bnst, const float* __restrict__ bng,
    const float* __restrict__ bnb, float invM,
    const short* __restrict__ Whi, const short* __restrict__ Wlo,
    const float* __restrict__ bias, float* __restrict__ outp,
    float* __restrict__ stats_out, int M, int K, int C) {
  const int tid = threadIdx.x, lane = tid & 63, w = tid >> 6;
  const int rtile = w & 1, cq = w >> 1;
  const int li = lane & 15, g = lane >> 4;
  const int row0 = blockIdx.x * 32;
  const int ct0 = cq * NCTQ;
  const int grow = row0 + rtile * 16 + li;
  const float* arow = A + (size_t)grow * K;
  const float* arow2 = A2 ? A2 + (size_t)grow * K : nullptr;
  f32x4 acc[NCTQ];
#pragma unroll
  for (int t = 0; t < NCTQ; ++t) acc[t] = (f32x4){0.f, 0.f, 0.f, 0.f};
  for (int ks = 0; ks < NKS; ++ks) {
    int k0 = ks * 32 + g * 8;
    short8v fh, fl;
    if (grow < M && k0 + 7 < K) {
      f32x4 q0 = *(const f32x4*)(arow + k0);
      f32x4 q1 = *(const f32x4*)(arow + k0 + 4);
      if (arow2) {
        f32x4 u0 = *(const f32x4*)(arow2 + k0);
        f32x4 u1 = *(const f32x4*)(arow2 + k0 + 4);
#pragma unroll
        for (int j = 0; j < 4; ++j) { q0[j] += u0[j]; q1[j] += u1[j]; }
      }
      if (BNIN) {
        f32x4 s0 = *(const f32x4*)(bnst + k0);
        f32x4 s1 = *(const f32x4*)(bnst + k0 + 4);
        f32x4 q20 = *(const f32x4*)(bnst + K + k0);
        f32x4 q21 = *(const f32x4*)(bnst + K + k0 + 4);
        f32x4 g0 = *(const f32x4*)(bng + k0);
        f32x4 g1 = *(const f32x4*)(bng + k0 + 4);
        f32x4 b0 = *(const f32x4*)(bnb + k0);
        f32x4 b1v = *(const f32x4*)(bnb + k0 + 4);
#pragma unroll
        for (int j = 0; j < 4; ++j) {
          float m = s0[j] * invM, vv = q20[j] * invM - m * m;
          q0[j] = fmaxf(g0[j] * (q0[j] - m) * rsqrtf(vv + 1e-5f) + b0[j], 0.f);
          m = s1[j] * invM; vv = q21[j] * invM - m * m;
          q1[j] = fmaxf(g1[j] * (q1[j] - m) * rsqrtf(vv + 1e-5f) + b1v[j], 0.f);
        }
      }
      cvt8(q0, q1, fh, fl);
    } else {
#pragma unroll
      for (int j = 0; j < 8; ++j) {
        int k = k0 + j;
        float v = 0.f;
        if (grow < M && k < K) {
          v = arow[k];
          if (arow2) v += arow2[k];
          if (BNIN) {
            float m = bnst[k] * invM, vv = bnst[K + k] * invM - m * m;
            v = fmaxf(bng[k] * (v - m) * rsqrtf(vv + 1e-5f) + bnb[k], 0.f);
          }
        }
        short hi = f2bf(v); fh[j] = hi; fl[j] = f2bf(v - bf2f(hi));
      }
    }
    const short8v* whp = (const short8v*)Whi + ((size_t)ct0 * NKS + ks) * 64 + lane;
    const short8v* wlp = (const short8v*)Wlo + ((size_t)ct0 * NKS + ks) * 64 + lane;
#pragma unroll
    for (int t = 0; t < NCTQ; ++t) {
      short8v wh = whp[(size_t)t * NKS * 64];
      short8v wl = wlp[(size_t)t * NKS * 64];
      acc[t] = __builtin_amdgcn_mfma_f32_16x16x32_bf16(fh, wh, acc[t], 0, 0, 0);
      acc[t] = __builtin_amdgcn_mfma_f32_16x16x32_bf16(fl, wh, acc[t], 0, 0, 0);
      acc[t] = __builtin_amdgcn_mfma_f32_16x16x32_bf16(fh, wl, acc[t], 0, 0, 0);
    }
  }
#pragma unroll
  for (int t = 0; t < NCTQ; ++t) {
    int c = (ct0 + t) * 16 + li;
    if (c < C) {
      float bb = bias[c];
      float s = 0.f, sq = 0.f;
#pragma unroll
      for (int q = 0; q < 4; ++q) {
        int gr = row0 + rtile * 16 + g * 4 + q;
        if (gr < M) {
          float val = acc[t][q] + bb;
          outp[(size_t)gr * C + c] = val;
          s += val;
          sq += val * val;
        }
      }
      if (STATS) {
        s += __shfl_xor(s, 16);  s += __shfl_xor(s, 32);
        sq += __shfl_xor(sq, 16); sq += __shfl_xor(sq, 32);
        if (g == 0) {
          unsafeAtomicAdd(&stats_out[c], s);
          unsafeAtomicAdd(&stats_out[C + c], sq);
        }
      }
    }
  }
}

// ---------- graph structure build (once per call) ----------
__global__ __launch_bounds__(256) void k_scatter(const int* __restrict__ dst,
                                                 int* __restrict__ cnt,
                                                 int* __restrict__ bucket,
                                                 int* __restrict__ ovf,
                                                 int* __restrict__ ovf_cnt, int E) {
  int e = blockIdx.x * 256 + threadIdx.x;
  if (e >= E) return;
  int d = dst[e];
  int pos = atomicAdd(&cnt[d], 1);
  if (pos < CAP) bucket[d * CAP + pos] = e;
  else {
    int p2 = atomicAdd(ovf_cnt, 1);
    if (p2 < OVF_MAX) ovf[p2] = e;
  }
}

__global__ __launch_bounds__(256) void k_bounds(const int* __restrict__ batch,
                                                int* __restrict__ start, int N, int B) {
  int n = blockIdx.x * 256 + threadIdx.x;
  if (n >= N) return;
  int b = batch[n];
  int bp = (n == 0) ? -1 : batch[n - 1];
  for (int g = bp + 1; g <= b; ++g) start[g] = n;
  if (n == N - 1)
    for (int g = b + 1; g <= B; ++g) start[g] = N;
}

// ---------- aggregation: pre(split) = h[n]+vn[bn] + sum relu(h[s]+vn[bs]+bond) ----------
__global__ __launch_bounds__(256) void k_aggr(const float* __restrict__ h,
                                              const float* __restrict__ vn,
                                              const float* __restrict__ bond,
                                              const int* __restrict__ batch,
                                              const int* __restrict__ src,
                                              const int* __restrict__ dst,
                                              const int* __restrict__ ea,
                                              const int* __restrict__ bucket,
                                              const int* __restrict__ cnt,
                                              const int* __restrict__ ovf,
                                              const int* __restrict__ ovfc,
                                              unsigned short* __restrict__ ph,
                                              unsigned short* __restrict__ pl, int N) {
  int n = (blockIdx.x * 256 + threadIdx.x) >> 6;
  int lane = threadIdx.x & 63;
  if (n >= N) return;
  int bn = batch[n];
  const float* hn = h + (size_t)n * HD;
  const float* vp = vn + (size_t)bn * HD;
  float acc[5];
#pragma unroll
  for (int j = 0; j < 5; ++j) {
    int col = lane + j * 64;
    acc[j] = (col < HD) ? hn[col] + vp[col] : 0.f;
  }
  int c = cnt[n];
  int cb = min(c, CAP);
  for (int i = 0; i < cb; ++i) {
    int e = bucket[n * CAP + i];
    int s = src[e], a = ea[e], bs = batch[s];
    const float* hs = h + (size_t)s * HD;
    const float* vs = vn + (size_t)bs * HD;
    const float* bb = bond + (size_t)a * HD;
#pragma unroll
    for (int j = 0; j < 5; ++j) {
      int col = lane + j * 64;
      if (col < HD) acc[j] += fmaxf(hs[col] + vs[col] + bb[col], 0.f);
    }
  }
  if (c > CAP) {  // rare: scan small overflow list
    int nov = min(*ovfc, OVF_MAX);
    for (int i = 0; i < nov; ++i) {
      int e = ovf[i];
      if (dst[e] != n) continue;
      int s = src[e], a = ea[e], bs = batch[s];
      const float* hs = h + (size_t)s * HD;
      const float* vs = vn + (size_t)bs * HD;
      const float* bb = bond + (size_t)a * HD;
#pragma unroll
      for (int j = 0; j < 5; ++j) {
        int col = lane + j * 64;
        if (col < HD) acc[j] += fmaxf(hs[col] + vs[col] + bb[col], 0.f);
      }
    }
  }
  unsigned short* phr = ph + (size_t)n * HDP;
  unsigned short* plr = pl + (size_t)n * HDP;
#pragma unroll
  for (int j = 0; j < 5; ++j) {
    int col = lane + j * 64;
    if (col < HDP) {
      float v = (col < HD) ? acc[j] : 0.f;
      short hi = f2bf(v);
      phr[col] = (unsigned short)hi;
      plr[col] = (unsigned short)f2bf(v - bf2f(hi));
    }
  }
}

// ---------- fused BN apply + segment pooling (one block per graph) ----------
__global__ __launch_bounds__(64) void k_bn_pool(const float* __restrict__ x,
                                                const float* __restrict__ gw,
                                                const float* __restrict__ bw,
                                                const float* __restrict__ stats,
                                                float invM,
                                                const int* __restrict__ start,
                                                int relu, float* __restrict__ hout,
                                                float* __restrict__ pooled) {
  int grf = blockIdx.x, lane = threadIdx.x;
  int r0 = start[grf], r1 = start[grf + 1];
  float m[5], rs[5], gg[5], bb[5], acc[5];
#pragma unroll
  for (int j = 0; j < 5; ++j) {
    int col = lane + j * 64;
    acc[j] = 0.f;
    m[j] = 0.f; rs[j] = 0.f; gg[j] = 0.f; bb[j] = 0.f;
    if (col < HD) {
      float mm = stats[col] * invM;
      float vv = stats[HD + col] * invM - mm * mm;
      m[j] = mm; rs[j] = rsqrtf(vv + 1e-5f);
      gg[j] = gw[col]; bb[j] = bw[col];
    }
  }
  for (int r = r0; r < r1; ++r) {
    const float* xr = x + (size_t)r * HD;
    float* hr = hout ? hout + (size_t)r * HD : nullptr;
#pragma unroll
    for (int j = 0; j < 5; ++j) {
      int col = lane + j * 64;
      if (col < HD) {
        float val = gg[j] * (xr[col] - m[j]) * rs[j] + bb[j];
        if (relu) val = fmaxf(val, 0.f);
        if (hr) hr[col] = val;
        acc[j] += val;
      }
    }
  }
  float* op = pooled + (size_t)grf * HD;
#pragma unroll
  for (int j = 0; j < 5; ++j) {
    int col = lane + j * 64;
    if (col < HD) op[col] = acc[j];
  }
}

// plain BN apply (vt2 -> vn)
__global__ __launch_bounds__(256) void k_bn_apply(const float* __restrict__ x,
                                                  const float* __restrict__ g,
                                                  const float* __restrict__ b,
                                                  const float* __restrict__ stats,
                                                  float invM, int C, int total, int relu,
                                                  float* __restrict__ out) {
  int idx = blockIdx.x * 256 + threadIdx.x;
  if (idx >= total) return;
  int n = idx / C, c = idx - n * C;
  float m = stats[c] * invM;
  float v = stats[C + c] * invM - m * m;
  float val = g[c] * (x[idx] - m) * rsqrtf(v + 1e-5f) + b[c];
  if (relu) val = fmaxf(val, 0.f);
  out[idx] = val;
}

// ---------- init ----------
__global__ __launch_bounds__(256) void k_init_h(const int* __restrict__ x,
                                                const float* __restrict__ emb,
                                                float* __restrict__ h, int nvec) {
  int idx = blockIdx.x * 256 + threadIdx.x;
  if (idx >= nvec) return;
  int n = idx / 75, c4 = idx - n * 75;
  ((float4*)h)[idx] = *(const float4*)(emb + (size_t)x[n] * HD + c4 * 4);
}

__global__ __launch_bounds__(256) void k_init_vn(const float* __restrict__ vn_emb,
                                                 float* __restrict__ vn, int total) {
  int idx = blockIdx.x * 256 + threadIdx.x;
  if (idx >= total) return;
  vn[idx] = vn_emb[idx % HD];
}

extern "C" void kernel_launch(void* const* d_in, const int* in_sizes, int n_in,
                              void* d_out, int out_size, void* d_ws, size_t ws_size,
                              hipStream_t stream) {
  const int N = in_sizes[0];        // 100000
  const int E = in_sizes[2];        // 200000
  const int B = out_size / HD;      // 4096

  const int* x     = (const int*)d_in[0];
  const int* src   = (const int*)d_in[1];
  const int* dst   = src + E;
  const int* ea    = (const int*)d_in[2];
  const int* batch = (const int*)d_in[3];
  const float* atom_emb = (const float*)d_in[5];
  const float* bond_emb = (const float*)d_in[6];
  const float* vn_emb   = (const float*)d_in[7];
  const float* W1   = (const float*)d_in[8];
  const float* b1   = (const float*)d_in[9];
  const float* W2   = (const float*)d_in[10];
  const float* b2   = (const float*)d_in[11];
  const float* bn_g = (const float*)d_in[12];
  const float* bn_b = (const float*)d_in[13];
  const float* vW1  = (const float*)d_in[14];
  const float* vb1  = (const float*)d_in[15];
  const float* vg1  = (const float*)d_in[16];
  const float* vbb1 = (const float*)d_in[17];
  const float* vW2  = (const float*)d_in[18];
  const float* vb2  = (const float*)d_in[19];
  const float* vg2  = (const float*)d_in[20];
  const float* vbb2 = (const float*)d_in[21];

  const size_t NH = (size_t)N * HD;
  const size_t BH = (size_t)B * HD;
  const size_t T1 = (size_t)CT1P * KS1 * 512;  // 204,800 shorts
  const size_t T2 = (size_t)CT2P * KS2 * 512;  // 194,560 shorts
  const size_t NPAD = (size_t)N + 64;          // ph/pl row padding (tail safety)

  // ---- workspace layout ----
  char* base = (char*)d_ws;
  size_t off = 0;
  float* h     = (float*)(base + off); off += NH * 4;
  unsigned short* ph = (unsigned short*)(base + off); off += NPAD * HDP * 2;
  unsigned short* pl = (unsigned short*)(base + off); off += NPAD * HDP * 2;
  float* vn    = (float*)(base + off); off += BH * 4;
  float* vt1   = (float*)(base + off); off += (size_t)B * HD2 * 4;
  float* pool  = (float*)(base + off); off += BH * 4;   // aliased as vt2
  float* vt2   = pool;
  float* stats = (float*)(base + off); off += 12000 * 4;
  int* cnt     = (int*)(base + off); off += (size_t)N * 4;
  int* ovfc    = (int*)(base + off); off += 4;
  int* ovf     = (int*)(base + off); off += (size_t)OVF_MAX * 4;
  int* start   = (int*)(base + off); off += (size_t)(B + 1) * 4;
  int* bucket  = (int*)(base + off); off += (size_t)N * CAP * 4;
  off = (off + 15) & ~(size_t)15;
  short* Ahi   = (short*)(base + off); off += T1 * 2;
  short* Alo   = (short*)(base + off); off += T1 * 2;
  short* Bhi   = (short*)(base + off); off += T2 * 2;
  short* Blo   = (short*)(base + off); off += T2 * 2;
  const size_t need_base = off;
  // optional dedicated VN frag buffers (prep once instead of per layer)
  short* vAhi = (short*)(base + off); off += T1 * 2;
  short* vAlo = (short*)(base + off); off += T1 * 2;
  short* vBhi = (short*)(base + off); off += T2 * 2;
  short* vBlo = (short*)(base + off); off += T2 * 2;
  const size_t need_full = off;
  const bool hoist_vw = (ws_size >= need_full);
  if (ws_size < need_base) {  // diagnostic fallback
    hipMemsetAsync(d_out, 0, (size_t)out_size * sizeof(float), stream);
    return;
  }
  if (!hoist_vw) { vAhi = Ahi; vAlo = Alo; vBhi = Bhi; vBlo = Blo; }

  // stats | cnt | ovfc are contiguous -> single memset
  hipMemsetAsync(stats, 0, 12000 * sizeof(float) + ((size_t)N + 1) * sizeof(int), stream);

  k_scatter<<<(E + 255) / 256, 256, 0, stream>>>(dst, cnt, bucket, ovf, ovfc, E);
  k_bounds<<<(N + 255) / 256, 256, 0, stream>>>(batch, start, N, B);

  const int totBH = (int)BH;
  const int nvNH = (int)NH / 4;
  const int t1 = (int)T1, t2 = (int)T2;
  k_init_h<<<(nvNH + 255) / 256, 256, 0, stream>>>(x, atom_emb, h, nvNH);
  k_init_vn<<<(totBH + 255) / 256, 256, 0, stream>>>(vn_emb, vn, totBH);
  if (hoist_vw) {
    k_prep_wf<<<(t1 + 255) / 256, 256, 0, stream>>>(vW1, vAhi, vAlo, HD, HD2, KS1, t1);
    k_prep_wf<<<(t2 + 255) / 256, 256, 0, stream>>>(vW2, vBhi, vBlo, HD2, HD, KS2, t2);
  }

  for (int i = 0; i < NLAYER; ++i) {
    float* stL  = stats + i * 2400;
    float* stV1 = stL + 2 * HD;
    float* stV2 = stV1 + 2 * HD2;
    const int last = (i == NLAYER - 1);
    float* pool_i = last ? (float*)d_out : pool;

    k_prep_wf<<<(t1 + 255) / 256, 256, 0, stream>>>(
        W1 + (size_t)i * HD * HD2, Ahi, Alo, HD, HD2, KS1, t1);
    k_prep_wf<<<(t2 + 255) / 256, 256, 0, stream>>>(
        W2 + (size_t)i * HD2 * HD, Bhi, Blo, HD2, HD, KS2, t2);

    k_aggr<<<(N * 64 + 255) / 256, 256, 0, stream>>>(
        h, vn, bond_emb, batch, src, dst, ea, bucket, cnt, ovf, ovfc, ph, pl, N);
    k_mlp_mfma<<<(N + 31) / 32, 512, 0, stream>>>(
        ph, pl, Ahi, Alo, b1 + (size_t)i * HD2, Bhi, Blo, b2 + (size_t)i * HD,
        h, stL, N);
    k_bn_pool<<<B, 64, 0, stream>>>(h, bn_g + i * HD, bn_b + i * HD, stL,
                                    1.f / (float)N, start, last ? 0 : 1,
                                    last ? nullptr : h, pool_i);

    if (!last) {
      if (!hoist_vw) {
        k_prep_wf<<<(t1 + 255) / 256, 256, 0, stream>>>(vW1, vAhi, vAlo, HD, HD2, KS1, t1);
      }
      k_gemm_mfma<KS1, 10, false, true><<<B / 32, 512, 0, stream>>>(
          pool, vn, nullptr, nullptr, nullptr, 0.f, vAhi, vAlo, vb1, vt1, stV1, B, HD, HD2);
      if (!hoist_vw) {
        k_prep_wf<<<(t2 + 255) / 256, 256, 0, stream>>>(vW2, vBhi, vBlo, HD2, HD, KS2, t2);
      }
      k_gemm_mfma<KS2, 5, true, true><<<B / 32, 512, 0, stream>>>(
          vt1, nullptr, stV1, vg1, vbb1, 1.f / (float)B, vBhi, vBlo, vb2, vt2, stV2, B, HD2, HD);
      k_bn_apply<<<(totBH + 255) / 256, 256, 0, stream>>>(
          vt2, vg2, vbb2, stV2, 1.f / (float)B, HD, totBH, 1, vn);
    }
  }
}

// Round 15
// 3787.174 us; speedup vs baseline: 1.6310x; 1.6310x over previous
//
#include <hip/hip_runtime.h>
#include <hip/hip_bf16.h>

// vGINMolEncoder: 5-layer GINE + virtual node, H=300, f32 in/out.
// Round 15: restore round-13/round-10 configuration exactly (best measured
// 3.68-3.75 ms). r9/r11-12/r14 all proved: any occupancy-raising variant
// (64-row tile, 16KB LDS, 8-wave block) trips the allocator to a 64-VGPR
// budget < the ~80-VGPR live set -> scratch spill -> regression. (256,3),
// 4 waves x 2 row-tiles, 40,960B LDS is the no-spill operating point.
// Split-bf16 (hi+lo) MFMA, f32 accum.

#define HD 300
#define HD2 600
#define HDP 304   // padded pre row (shorts)
#define NLAYER 5
#define KS1 10   // 320/32
#define KS2 19   // 608/32
#define CT1P 40  // padded hidden col tiles (38 real)
#define CT2P 20  // padded out col tiles (19 real)
#define CAP 8
#define OVF_MAX 8192

typedef __attribute__((ext_vector_type(8))) short short8v;
typedef __attribute__((ext_vector_type(4))) short short4v;
typedef __attribute__((ext_vector_type(4))) float f32x4;

__device__ __forceinline__ short f2bf(float x) {  // RNE f32->bf16
  union { float f; unsigned u; } v; v.f = x;
  unsigned r = v.u + 0x7fffu + ((v.u >> 16) & 1u);
  return (short)(r >> 16);
}
__device__ __forceinline__ float bf2f(short h) {
  union { unsigned u; float f; } v; v.u = ((unsigned)(unsigned short)h) << 16;
  return v.f;
}

__device__ __forceinline__ void cvt8(f32x4 x0, f32x4 x1, short8v& fh, short8v& fl) {
#pragma unroll
  for (int j = 0; j < 4; ++j) { short hi = f2bf(x0[j]); fh[j] = hi; fl[j] = f2bf(x0[j] - bf2f(hi)); }
#pragma unroll
  for (int j = 0; j < 4; ++j) { short hi = f2bf(x1[j]); fh[4 + j] = hi; fl[4 + j] = f2bf(x1[j] - bf2f(hi)); }
}

// ---------- weight repack to hi/lo fragment order ----------
__global__ __launch_bounds__(256) void k_prep_wf(const float* __restrict__ W,
                                                 short* __restrict__ Whi,
                                                 short* __restrict__ Wlo,
                                                 int K, int C, int nks, int total) {
  int idx = blockIdx.x * 256 + threadIdx.x;
  if (idx >= total) return;
  int j = idx & 7, lane = (idx >> 3) & 63, t = idx >> 9;
  int ks = t % nks, ct = t / nks;
  int k = ks * 32 + (lane >> 4) * 8 + j;
  int c = ct * 16 + (lane & 15);
  float w = (k < K && c < C) ? W[(size_t)k * C + c] : 0.f;
  short hi = f2bf(w);
  Whi[idx] = hi;
  Wlo[idx] = f2bf(w - bf2f(hi));
}

// ---------- fused node MLP + BN-stats (proven 32-row, 4-wave structure) ----------
__global__ __launch_bounds__(256, 3) void k_mlp_mfma(
    const unsigned short* __restrict__ ph, const unsigned short* __restrict__ pl,
    const short* __restrict__ W1hi, const short* __restrict__ W1lo,
    const float* __restrict__ b1,
    const short* __restrict__ W2hi, const short* __restrict__ W2lo,
    const float* __restrict__ b2, float* __restrict__ out,
    float* __restrict__ stats, int N) {
  __shared__ __align__(16) short hidh[32 * 320];  // 20,480 B
  __shared__ __align__(16) short hidl[32 * 320];  // 20,480 B
  char* hbh = (char*)hidh;
  char* hbl = (char*)hidl;
  const int tid = threadIdx.x;
  const int lane = tid & 63, cq = tid >> 6;   // 4 waves = 4 col-quarters
  const int li = lane & 15, g = lane >> 4;
  const int row0 = blockIdx.x * 32;
  const size_t r0b = (size_t)(row0 + li) * HDP;       // act row rt=0
  const size_t r1b = (size_t)(row0 + 16 + li) * HDP;  // act row rt=1

  f32x4 acc2[2][5];
#pragma unroll
  for (int rt = 0; rt < 2; ++rt)
#pragma unroll
    for (int t = 0; t < 5; ++t) acc2[rt][t] = (f32x4){0.f, 0.f, 0.f, 0.f};

#pragma unroll 1
  for (int hf = 0; hf < 2; ++hf) {
    const int ct0 = hf * 20 + cq * 5;
    // ---- phase 1: hidden ctiles [ct0, ct0+5) ----
    f32x4 acc1[2][5];
#pragma unroll
    for (int rt = 0; rt < 2; ++rt)
#pragma unroll
      for (int t = 0; t < 5; ++t) acc1[rt][t] = (f32x4){0.f, 0.f, 0.f, 0.f};
    for (int ks = 0; ks < KS1; ++ks) {
      int k0 = ks * 32 + g * 8;
      short8v a0h = *(const short8v*)(ph + r0b + k0);
      short8v a0l = *(const short8v*)(pl + r0b + k0);
      short8v a1h = *(const short8v*)(ph + r1b + k0);
      short8v a1l = *(const short8v*)(pl + r1b + k0);
      const short8v* whp = (const short8v*)W1hi + ((size_t)ct0 * KS1 + ks) * 64 + lane;
      const short8v* wlp = (const short8v*)W1lo + ((size_t)ct0 * KS1 + ks) * 64 + lane;
#pragma unroll
      for (int ct = 0; ct < 5; ++ct) {
        short8v wh = whp[(size_t)ct * KS1 * 64];
        short8v wl = wlp[(size_t)ct * KS1 * 64];
        acc1[0][ct] = __builtin_amdgcn_mfma_f32_16x16x32_bf16(wh, a0h, acc1[0][ct], 0, 0, 0);
        acc1[0][ct] = __builtin_amdgcn_mfma_f32_16x16x32_bf16(wh, a0l, acc1[0][ct], 0, 0, 0);
        acc1[0][ct] = __builtin_amdgcn_mfma_f32_16x16x32_bf16(wl, a0h, acc1[0][ct], 0, 0, 0);
        acc1[1][ct] = __builtin_amdgcn_mfma_f32_16x16x32_bf16(wh, a1h, acc1[1][ct], 0, 0, 0);
        acc1[1][ct] = __builtin_amdgcn_mfma_f32_16x16x32_bf16(wh, a1l, acc1[1][ct], 0, 0, 0);
        acc1[1][ct] = __builtin_amdgcn_mfma_f32_16x16x32_bf16(wl, a1h, acc1[1][ct], 0, 0, 0);
      }
    }
    if (hf) __syncthreads();  // prior half's phase-2 reads done
    // bias + relu -> split-bf16 LDS (convert once at write)
#pragma unroll
    for (int ct = 0; ct < 5; ++ct) {
      int ctile = ct0 + ct, cc = ctile - hf * 20;
      float bb[4];
#pragma unroll
      for (int q = 0; q < 4; ++q) {
        int c = ctile * 16 + g * 4 + q;
        bb[q] = (c < HD2) ? b1[c] : 0.f;
      }
#pragma unroll
      for (int rt = 0; rt < 2; ++rt) {
        short4v vh, vl;
#pragma unroll
        for (int q = 0; q < 4; ++q) {
          float v = fmaxf(acc1[rt][ct][q] + bb[q], 0.f);
          short hi = f2bf(v);
          vh[q] = hi;
          vl[q] = f2bf(v - bf2f(hi));
        }
        int row = rt * 16 + li;
        int lin = row * 640 + cc * 32 + g * 8;
        int sw = (row & 7) << 4;
        *(short4v*)(hbh + (lin ^ sw)) = vh;
        *(short4v*)(hbl + (lin ^ sw)) = vl;
      }
    }
    __syncthreads();
    // ---- phase 2 partial: ks of this half (pure ds_read + MFMA) ----
    const int nks2 = hf ? 9 : 10;
    for (int ksl = 0; ksl < nks2; ++ksl) {
      int ksg = hf * 10 + ksl;
      int lin0 = li * 640 + ksl * 64 + g * 16;
      int sw0 = (li & 7) << 4;
      int lin1 = (16 + li) * 640 + ksl * 64 + g * 16;
      int sw1 = ((16 + li) & 7) << 4;
      short8v hh0 = *(const short8v*)(hbh + (lin0 ^ sw0));
      short8v hl0 = *(const short8v*)(hbl + (lin0 ^ sw0));
      short8v hh1 = *(const short8v*)(hbh + (lin1 ^ sw1));
      short8v hl1 = *(const short8v*)(hbl + (lin1 ^ sw1));
      const short8v* w2h = (const short8v*)W2hi + ((size_t)(cq * 5) * KS2 + ksg) * 64 + lane;
      const short8v* w2l = (const short8v*)W2lo + ((size_t)(cq * 5) * KS2 + ksg) * 64 + lane;
#pragma unroll
      for (int t = 0; t < 5; ++t) {
        short8v wh = w2h[(size_t)t * KS2 * 64];
        short8v wl = w2l[(size_t)t * KS2 * 64];
        acc2[0][t] = __builtin_amdgcn_mfma_f32_16x16x32_bf16(hh0, wh, acc2[0][t], 0, 0, 0);
        acc2[0][t] = __builtin_amdgcn_mfma_f32_16x16x32_bf16(hl0, wh, acc2[0][t], 0, 0, 0);
        acc2[0][t] = __builtin_amdgcn_mfma_f32_16x16x32_bf16(hh0, wl, acc2[0][t], 0, 0, 0);
        acc2[1][t] = __builtin_amdgcn_mfma_f32_16x16x32_bf16(hh1, wh, acc2[1][t], 0, 0, 0);
        acc2[1][t] = __builtin_amdgcn_mfma_f32_16x16x32_bf16(hl1, wh, acc2[1][t], 0, 0, 0);
        acc2[1][t] = __builtin_amdgcn_mfma_f32_16x16x32_bf16(hh1, wl, acc2[1][t], 0, 0, 0);
      }
    }
  }
  // epilogue: bias, store, fused column stats (guarded for tail rows)
#pragma unroll
  for (int t = 0; t < 5; ++t) {
    int c2 = (cq * 5 + t) * 16 + li;
    if (c2 < HD) {
      float bb = b2[c2];
      float s = 0.f, sq = 0.f;
#pragma unroll
      for (int rt = 0; rt < 2; ++rt) {
#pragma unroll
        for (int q = 0; q < 4; ++q) {
          int gr = row0 + rt * 16 + g * 4 + q;
          if (gr < N) {
            float val = acc2[rt][t][q] + bb;
            out[(size_t)gr * HD + c2] = val;
            s += val;
            sq += val * val;
          }
        }
      }
      s += __shfl_xor(s, 16);  s += __shfl_xor(s, 32);
      sq += __shfl_xor(sq, 16); sq += __shfl_xor(sq, 32);
      if (g == 0) {
        unsafeAtomicAdd(&stats[c2], s);
        unsafeAtomicAdd(&stats[HD + c2], sq);
      }
    }
  }
}

// ---------- generic split-bf16 MFMA GEMM for VN MLP ----------
// BNIN: apply BN(bnst,invM)+relu to A inline.  STATS: fused column stats out.
template <int NKS, int NCTQ, bool BNIN, bool STATS>
__global__ __launch_bounds__(512, 2) void k_gemm_mfma(
    const float* __restrict__ A, const float* __restrict__ A2,
    const float* __restrict__ bnst, const float* __restrict__ bng,
    const float* __restrict__ bnb, float invM,
    const short* __restrict__ Whi, const short* __restrict__ Wlo,
    const float* __restrict__ bias, float* __restrict__ outp,
    float* __restrict__ stats_out, int M, int K, int C) {
  const int tid = threadIdx.x, lane = tid & 63, w = tid >> 6;
  const int rtile = w & 1, cq = w >> 1;
  const int li = lane & 15, g = lane >> 4;
  const int row0 = blockIdx.x * 32;
  const int ct0 = cq * NCTQ;
  const int grow = row0 + rtile * 16 + li;
  const float* arow = A + (size_t)grow * K;
  const float* arow2 = A2 ? A2 + (size_t)grow * K : nullptr;
  f32x4 acc[NCTQ];
#pragma unroll
  for (int t = 0; t < NCTQ; ++t) acc[t] = (f32x4){0.f, 0.f, 0.f, 0.f};
  for (int ks = 0; ks < NKS; ++ks) {
    int k0 = ks * 32 + g * 8;
    short8v fh, fl;
    if (grow < M && k0 + 7 < K) {
      f32x4 q0 = *(const f32x4*)(arow + k0);
      f32x4 q1 = *(const f32x4*)(arow + k0 + 4);
      if (arow2) {
        f32x4 u0 = *(const f32x4*)(arow2 + k0);
        f32x4 u1 = *(const f32x4*)(arow2 + k0 + 4);
#pragma unroll
        for (int j = 0; j < 4; ++j) { q0[j] += u0[j]; q1[j] += u1[j]; }
      }
      if (BNIN) {
        f32x4 s0 = *(const f32x4*)(bnst + k0);
        f32x4 s1 = *(const f32x4*)(bnst + k0 + 4);
        f32x4 q20 = *(const f32x4*)(bnst + K + k0);
        f32x4 q21 = *(const f32x4*)(bnst + K + k0 + 4);
        f32x4 g0 = *(const f32x4*)(bng + k0);
        f32x4 g1 = *(const f32x4*)(bng + k0 + 4);
        f32x4 b0 = *(const f32x4*)(bnb + k0);
        f32x4 b1v = *(const f32x4*)(bnb + k0 + 4);
#pragma unroll
        for (int j = 0; j < 4; ++j) {
          float m = s0[j] * invM, vv = q20[j] * invM - m * m;
          q0[j] = fmaxf(g0[j] * (q0[j] - m) * rsqrtf(vv + 1e-5f) + b0[j], 0.f);
          m = s1[j] * invM; vv = q21[j] * invM - m * m;
          q1[j] = fmaxf(g1[j] * (q1[j] - m) * rsqrtf(vv + 1e-5f) + b1v[j], 0.f);
        }
      }
      cvt8(q0, q1, fh, fl);
    } else {
#pragma unroll
      for (int j = 0; j < 8; ++j) {
        int k = k0 + j;
        float v = 0.f;
        if (grow < M && k < K) {
          v = arow[k];
          if (arow2) v += arow2[k];
          if (BNIN) {
            float m = bnst[k] * invM, vv = bnst[K + k] * invM - m * m;
            v = fmaxf(bng[k] * (v - m) * rsqrtf(vv + 1e-5f) + bnb[k], 0.f);
          }
        }
        short hi = f2bf(v); fh[j] = hi; fl[j] = f2bf(v - bf2f(hi));
      }
    }
    const short8v* whp = (const short8v*)Whi + ((size_t)ct0 * NKS + ks) * 64 + lane;
    const short8v* wlp = (const short8v*)Wlo + ((size_t)ct0 * NKS + ks) * 64 + lane;
#pragma unroll
    for (int t = 0; t < NCTQ; ++t) {
      short8v wh = whp[(size_t)t * NKS * 64];
      short8v wl = wlp[(size_t)t * NKS * 64];
      acc[t] = __builtin_amdgcn_mfma_f32_16x16x32_bf16(fh, wh, acc[t], 0, 0, 0);
      acc[t] = __builtin_amdgcn_mfma_f32_16x16x32_bf16(fl, wh, acc[t], 0, 0, 0);
      acc[t] = __builtin_amdgcn_mfma_f32_16x16x32_bf16(fh, wl, acc[t], 0, 0, 0);
    }
  }
#pragma unroll
  for (int t = 0; t < NCTQ; ++t) {
    int c = (ct0 + t) * 16 + li;
    if (c < C) {
      float bb = bias[c];
      float s = 0.f, sq = 0.f;
#pragma unroll
      for (int q = 0; q < 4; ++q) {
        int gr = row0 + rtile * 16 + g * 4 + q;
        if (gr < M) {
          float val = acc[t][q] + bb;
          outp[(size_t)gr * C + c] = val;
          s += val;
          sq += val * val;
        }
      }
      if (STATS) {
        s += __shfl_xor(s, 16);  s += __shfl_xor(s, 32);
        sq += __shfl_xor(sq, 16); sq += __shfl_xor(sq, 32);
        if (g == 0) {
          unsafeAtomicAdd(&stats_out[c], s);
          unsafeAtomicAdd(&stats_out[C + c], sq);
        }
      }
    }
  }
}

// ---------- graph structure build (once per call) ----------
__global__ __launch_bounds__(256) void k_scatter(const int* __restrict__ dst,
                                                 int* __restrict__ cnt,
                                                 int* __restrict__ bucket,
                                                 int* __restrict__ ovf,
                                                 int* __restrict__ ovf_cnt, int E) {
  int e = blockIdx.x * 256 + threadIdx.x;
  if (e >= E) return;
  int d = dst[e];
  int pos = atomicAdd(&cnt[d], 1);
  if (pos < CAP) bucket[d * CAP + pos] = e;
  else {
    int p2 = atomicAdd(ovf_cnt, 1);
    if (p2 < OVF_MAX) ovf[p2] = e;
  }
}

__global__ __launch_bounds__(256) void k_bounds(const int* __restrict__ batch,
                                                int* __restrict__ start, int N, int B) {
  int n = blockIdx.x * 256 + threadIdx.x;
  if (n >= N) return;
  int b = batch[n];
  int bp = (n == 0) ? -1 : batch[n - 1];
  for (int g = bp + 1; g <= b; ++g) start[g] = n;
  if (n == N - 1)
    for (int g = b + 1; g <= B; ++g) start[g] = N;
}

// ---------- aggregation: pre(split) = h[n]+vn[bn] + sum relu(h[s]+vn[bs]+bond) ----------
__global__ __launch_bounds__(256) void k_aggr(const float* __restrict__ h,
                                              const float* __restrict__ vn,
                                              const float* __restrict__ bond,
                                              const int* __restrict__ batch,
                                              const int* __restrict__ src,
                                              const int* __restrict__ dst,
                                              const int* __restrict__ ea,
                                              const int* __restrict__ bucket,
                                              const int* __restrict__ cnt,
                                              const int* __restrict__ ovf,
                                              const int* __restrict__ ovfc,
                                              unsigned short* __restrict__ ph,
                                              unsigned short* __restrict__ pl, int N) {
  int n = (blockIdx.x * 256 + threadIdx.x) >> 6;
  int lane = threadIdx.x & 63;
  if (n >= N) return;
  int bn = batch[n];
  const float* hn = h + (size_t)n * HD;
  const float* vp = vn + (size_t)bn * HD;
  float acc[5];
#pragma unroll
  for (int j = 0; j < 5; ++j) {
    int col = lane + j * 64;
    acc[j] = (col < HD) ? hn[col] + vp[col] : 0.f;
  }
  int c = cnt[n];
  int cb = min(c, CAP);
  for (int i = 0; i < cb; ++i) {
    int e = bucket[n * CAP + i];
    int s = src[e], a = ea[e], bs = batch[s];
    const float* hs = h + (size_t)s * HD;
    const float* vs = vn + (size_t)bs * HD;
    const float* bb = bond + (size_t)a * HD;
#pragma unroll
    for (int j = 0; j < 5; ++j) {
      int col = lane + j * 64;
      if (col < HD) acc[j] += fmaxf(hs[col] + vs[col] + bb[col], 0.f);
    }
  }
  if (c > CAP) {  // rare: scan small overflow list
    int nov = min(*ovfc, OVF_MAX);
    for (int i = 0; i < nov; ++i) {
      int e = ovf[i];
      if (dst[e] != n) continue;
      int s = src[e], a = ea[e], bs = batch[s];
      const float* hs = h + (size_t)s * HD;
      const float* vs = vn + (size_t)bs * HD;
      const float* bb = bond + (size_t)a * HD;
#pragma unroll
      for (int j = 0; j < 5; ++j) {
        int col = lane + j * 64;
        if (col < HD) acc[j] += fmaxf(hs[col] + vs[col] + bb[col], 0.f);
      }
    }
  }
  unsigned short* phr = ph + (size_t)n * HDP;
  unsigned short* plr = pl + (size_t)n * HDP;
#pragma unroll
  for (int j = 0; j < 5; ++j) {
    int col = lane + j * 64;
    if (col < HDP) {
      float v = (col < HD) ? acc[j] : 0.f;
      short hi = f2bf(v);
      phr[col] = (unsigned short)hi;
      plr[col] = (unsigned short)f2bf(v - bf2f(hi));
    }
  }
}

// ---------- fused BN apply + segment pooling (one block per graph) ----------
__global__ __launch_bounds__(64) void k_bn_pool(const float* __restrict__ x,
                                                const float* __restrict__ gw,
                                                const float* __restrict__ bw,
                                                const float* __restrict__ stats,
                                                float invM,
                                                const int* __restrict__ start,
                                                int relu, float* __restrict__ hout,
                                                float* __restrict__ pooled) {
  int grf = blockIdx.x, lane = threadIdx.x;
  int r0 = start[grf], r1 = start[grf + 1];
  float m[5], rs[5], gg[5], bb[5], acc[5];
#pragma unroll
  for (int j = 0; j < 5; ++j) {
    int col = lane + j * 64;
    acc[j] = 0.f;
    m[j] = 0.f; rs[j] = 0.f; gg[j] = 0.f; bb[j] = 0.f;
    if (col < HD) {
      float mm = stats[col] * invM;
      float vv = stats[HD + col] * invM - mm * mm;
      m[j] = mm; rs[j] = rsqrtf(vv + 1e-5f);
      gg[j] = gw[col]; bb[j] = bw[col];
    }
  }
  for (int r = r0; r < r1; ++r) {
    const float* xr = x + (size_t)r * HD;
    float* hr = hout ? hout + (size_t)r * HD : nullptr;
#pragma unroll
    for (int j = 0; j < 5; ++j) {
      int col = lane + j * 64;
      if (col < HD) {
        float val = gg[j] * (xr[col] - m[j]) * rs[j] + bb[j];
        if (relu) val = fmaxf(val, 0.f);
        if (hr) hr[col] = val;
        acc[j] += val;
      }
    }
  }
  float* op = pooled + (size_t)grf * HD;
#pragma unroll
  for (int j = 0; j < 5; ++j) {
    int col = lane + j * 64;
    if (col < HD) op[col] = acc[j];
  }
}

// plain BN apply (vt2 -> vn)
__global__ __launch_bounds__(256) void k_bn_apply(const float* __restrict__ x,
                                                  const float* __restrict__ g,
                                                  const float* __restrict__ b,
                                                  const float* __restrict__ stats,
                                                  float invM, int C, int total, int relu,
                                                  float* __restrict__ out) {
  int idx = blockIdx.x * 256 + threadIdx.x;
  if (idx >= total) return;
  int n = idx / C, c = idx - n * C;
  float m = stats[c] * invM;
  float v = stats[C + c] * invM - m * m;
  float val = g[c] * (x[idx] - m) * rsqrtf(v + 1e-5f) + b[c];
  if (relu) val = fmaxf(val, 0.f);
  out[idx] = val;
}

// ---------- init ----------
__global__ __launch_bounds__(256) void k_init_h(const int* __restrict__ x,
                                                const float* __restrict__ emb,
                                                float* __restrict__ h, int nvec) {
  int idx = blockIdx.x * 256 + threadIdx.x;
  if (idx >= nvec) return;
  int n = idx / 75, c4 = idx - n * 75;
  ((float4*)h)[idx] = *(const float4*)(emb + (size_t)x[n] * HD + c4 * 4);
}

__global__ __launch_bounds__(256) void k_init_vn(const float* __restrict__ vn_emb,
                                                 float* __restrict__ vn, int total) {
  int idx = blockIdx.x * 256 + threadIdx.x;
  if (idx >= total) return;
  vn[idx] = vn_emb[idx % HD];
}

extern "C" void kernel_launch(void* const* d_in, const int* in_sizes, int n_in,
                              void* d_out, int out_size, void* d_ws, size_t ws_size,
                              hipStream_t stream) {
  const int N = in_sizes[0];        // 100000
  const int E = in_sizes[2];        // 200000
  const int B = out_size / HD;      // 4096

  const int* x     = (const int*)d_in[0];
  const int* src   = (const int*)d_in[1];
  const int* dst   = src + E;
  const int* ea    = (const int*)d_in[2];
  const int* batch = (const int*)d_in[3];
  const float* atom_emb = (const float*)d_in[5];
  const float* bond_emb = (const float*)d_in[6];
  const float* vn_emb   = (const float*)d_in[7];
  const float* W1   = (const float*)d_in[8];
  const float* b1   = (const float*)d_in[9];
  const float* W2   = (const float*)d_in[10];
  const float* b2   = (const float*)d_in[11];
  const float* bn_g = (const float*)d_in[12];
  const float* bn_b = (const float*)d_in[13];
  const float* vW1  = (const float*)d_in[14];
  const float* vb1  = (const float*)d_in[15];
  const float* vg1  = (const float*)d_in[16];
  const float* vbb1 = (const float*)d_in[17];
  const float* vW2  = (const float*)d_in[18];
  const float* vb2  = (const float*)d_in[19];
  const float* vg2  = (const float*)d_in[20];
  const float* vbb2 = (const float*)d_in[21];

  const size_t NH = (size_t)N * HD;
  const size_t BH = (size_t)B * HD;
  const size_t T1 = (size_t)CT1P * KS1 * 512;  // 204,800 shorts
  const size_t T2 = (size_t)CT2P * KS2 * 512;  // 194,560 shorts
  const size_t NPAD = (size_t)N + 64;          // ph/pl row padding (tail safety)

  // ---- workspace layout ----
  char* base = (char*)d_ws;
  size_t off = 0;
  float* h     = (float*)(base + off); off += NH * 4;
  unsigned short* ph = (unsigned short*)(base + off); off += NPAD * HDP * 2;
  unsigned short* pl = (unsigned short*)(base + off); off += NPAD * HDP * 2;
  float* vn    = (float*)(base + off); off += BH * 4;
  float* vt1   = (float*)(base + off); off += (size_t)B * HD2 * 4;
  float* pool  = (float*)(base + off); off += BH * 4;   // aliased as vt2
  float* vt2   = pool;
  float* stats = (float*)(base + off); off += 12000 * 4;
  int* cnt     = (int*)(base + off); off += (size_t)N * 4;
  int* ovfc    = (int*)(base + off); off += 4;
  int* ovf     = (int*)(base + off); off += (size_t)OVF_MAX * 4;
  int* start   = (int*)(base + off); off += (size_t)(B + 1) * 4;
  int* bucket  = (int*)(base + off); off += (size_t)N * CAP * 4;
  off = (off + 15) & ~(size_t)15;
  short* Ahi   = (short*)(base + off); off += T1 * 2;
  short* Alo   = (short*)(base + off); off += T1 * 2;
  short* Bhi   = (short*)(base + off); off += T2 * 2;
  short* Blo   = (short*)(base + off); off += T2 * 2;
  const size_t need_base = off;
  // optional dedicated VN frag buffers (prep once instead of per layer)
  short* vAhi = (short*)(base + off); off += T1 * 2;
  short* vAlo = (short*)(base + off); off += T1 * 2;
  short* vBhi = (short*)(base + off); off += T2 * 2;
  short* vBlo = (short*)(base + off); off += T2 * 2;
  const size_t need_full = off;
  const bool hoist_vw = (ws_size >= need_full);
  if (ws_size < need_base) {  // diagnostic fallback
    hipMemsetAsync(d_out, 0, (size_t)out_size * sizeof(float), stream);
    return;
  }
  if (!hoist_vw) { vAhi = Ahi; vAlo = Alo; vBhi = Bhi; vBlo = Blo; }

  // stats | cnt | ovfc are contiguous -> single memset
  hipMemsetAsync(stats, 0, 12000 * sizeof(float) + ((size_t)N + 1) * sizeof(int), stream);

  k_scatter<<<(E + 255) / 256, 256, 0, stream>>>(dst, cnt, bucket, ovf, ovfc, E);
  k_bounds<<<(N + 255) / 256, 256, 0, stream>>>(batch, start, N, B);

  const int totBH = (int)BH;
  const int nvNH = (int)NH / 4;
  const int t1 = (int)T1, t2 = (int)T2;
  k_init_h<<<(nvNH + 255) / 256, 256, 0, stream>>>(x, atom_emb, h, nvNH);
  k_init_vn<<<(totBH + 255) / 256, 256, 0, stream>>>(vn_emb, vn, totBH);
  if (hoist_vw) {
    k_prep_wf<<<(t1 + 255) / 256, 256, 0, stream>>>(vW1, vAhi, vAlo, HD, HD2, KS1, t1);
    k_prep_wf<<<(t2 + 255) / 256, 256, 0, stream>>>(vW2, vBhi, vBlo, HD2, HD, KS2, t2);
  }

  for (int i = 0; i < NLAYER; ++i) {
    float* stL  = stats + i * 2400;
    float* stV1 = stL + 2 * HD;
    float* stV2 = stV1 + 2 * HD2;
    const int last = (i == NLAYER - 1);
    float* pool_i = last ? (float*)d_out : pool;

    k_prep_wf<<<(t1 + 255) / 256, 256, 0, stream>>>(
        W1 + (size_t)i * HD * HD2, Ahi, Alo, HD, HD2, KS1, t1);
    k_prep_wf<<<(t2 + 255) / 256, 256, 0, stream>>>(
        W2 + (size_t)i * HD2 * HD, Bhi, Blo, HD2, HD, KS2, t2);

    k_aggr<<<(N * 64 + 255) / 256, 256, 0, stream>>>(
        h, vn, bond_emb, batch, src, dst, ea, bucket, cnt, ovf, ovfc, ph, pl, N);
    k_mlp_mfma<<<(N + 31) / 32, 256, 0, stream>>>(
        ph, pl, Ahi, Alo, b1 + (size_t)i * HD2, Bhi, Blo, b2 + (size_t)i * HD,
        h, stL, N);
    k_bn_pool<<<B, 64, 0, stream>>>(h, bn_g + i * HD, bn_b + i * HD, stL,
                                    1.f / (float)N, start, last ? 0 : 1,
                                    last ? nullptr : h, pool_i);

    if (!last) {
      if (!hoist_vw) {
        k_prep_wf<<<(t1 + 255) / 256, 256, 0, stream>>>(vW1, vAhi, vAlo, HD, HD2, KS1, t1);
      }
      k_gemm_mfma<KS1, 10, false, true><<<B / 32, 512, 0, stream>>>(
          pool, vn, nullptr, nullptr, nullptr, 0.f, vAhi, vAlo, vb1, vt1, stV1, B, HD, HD2);
      if (!hoist_vw) {
        k_prep_wf<<<(t2 + 255) / 256, 256, 0, stream>>>(vW2, vBhi, vBlo, HD2, HD, KS2, t2);
      }
      k_gemm_mfma<KS2, 5, true, true><<<B / 32, 512, 0, stream>>>(
          vt1, nullptr, stV1, vg1, vbb1, 1.f / (float)B, vBhi, vBlo, vb2, vt2, stV2, B, HD2, HD);
      k_bn_apply<<<(totBH + 255) / 256, 256, 0, stream>>>(
          vt2, vg2, vbb2, stV2, 1.f / (float)B, HD, totBH, 1, vn);
    }
  }
}

// Round 16
// 3564.242 us; speedup vs baseline: 1.7331x; 1.0625x over previous
//
#include <hip/hip_runtime.h>
#include <hip/hip_bf16.h>

// vGINMolEncoder: 5-layer GINE + virtual node, H=300, f32 in/out.
// Round 16: r15 MLP (proven no-spill point) unchanged; k_aggr and k_bn_pool
// vectorized to f32x4 (lane covers vec idx {lane, 64+lane<75}; 4x fewer
// instructions, same coalesced bytes). Split-bf16 (hi+lo) MFMA, f32 accum.

#define HD 300
#define HD2 600
#define HDP 304   // padded pre row (shorts)
#define NLAYER 5
#define KS1 10   // 320/32
#define KS2 19   // 608/32
#define CT1P 40  // padded hidden col tiles (38 real)
#define CT2P 20  // padded out col tiles (19 real)
#define CAP 8
#define OVF_MAX 8192

typedef __attribute__((ext_vector_type(8))) short short8v;
typedef __attribute__((ext_vector_type(4))) short short4v;
typedef __attribute__((ext_vector_type(4))) float f32x4;

__device__ __forceinline__ short f2bf(float x) {  // RNE f32->bf16
  union { float f; unsigned u; } v; v.f = x;
  unsigned r = v.u + 0x7fffu + ((v.u >> 16) & 1u);
  return (short)(r >> 16);
}
__device__ __forceinline__ float bf2f(short h) {
  union { unsigned u; float f; } v; v.u = ((unsigned)(unsigned short)h) << 16;
  return v.f;
}

__device__ __forceinline__ void cvt8(f32x4 x0, f32x4 x1, short8v& fh, short8v& fl) {
#pragma unroll
  for (int j = 0; j < 4; ++j) { short hi = f2bf(x0[j]); fh[j] = hi; fl[j] = f2bf(x0[j] - bf2f(hi)); }
#pragma unroll
  for (int j = 0; j < 4; ++j) { short hi = f2bf(x1[j]); fh[4 + j] = hi; fl[4 + j] = f2bf(x1[j] - bf2f(hi)); }
}

// ---------- weight repack to hi/lo fragment order ----------
__global__ __launch_bounds__(256) void k_prep_wf(const float* __restrict__ W,
                                                 short* __restrict__ Whi,
                                                 short* __restrict__ Wlo,
                                                 int K, int C, int nks, int total) {
  int idx = blockIdx.x * 256 + threadIdx.x;
  if (idx >= total) return;
  int j = idx & 7, lane = (idx >> 3) & 63, t = idx >> 9;
  int ks = t % nks, ct = t / nks;
  int k = ks * 32 + (lane >> 4) * 8 + j;
  int c = ct * 16 + (lane & 15);
  float w = (k < K && c < C) ? W[(size_t)k * C + c] : 0.f;
  short hi = f2bf(w);
  Whi[idx] = hi;
  Wlo[idx] = f2bf(w - bf2f(hi));
}

// ---------- fused node MLP + BN-stats (proven 32-row, 4-wave structure) ----------
__global__ __launch_bounds__(256, 3) void k_mlp_mfma(
    const unsigned short* __restrict__ ph, const unsigned short* __restrict__ pl,
    const short* __restrict__ W1hi, const short* __restrict__ W1lo,
    const float* __restrict__ b1,
    const short* __restrict__ W2hi, const short* __restrict__ W2lo,
    const float* __restrict__ b2, float* __restrict__ out,
    float* __restrict__ stats, int N) {
  __shared__ __align__(16) short hidh[32 * 320];  // 20,480 B
  __shared__ __align__(16) short hidl[32 * 320];  // 20,480 B
  char* hbh = (char*)hidh;
  char* hbl = (char*)hidl;
  const int tid = threadIdx.x;
  const int lane = tid & 63, cq = tid >> 6;   // 4 waves = 4 col-quarters
  const int li = lane & 15, g = lane >> 4;
  const int row0 = blockIdx.x * 32;
  const size_t r0b = (size_t)(row0 + li) * HDP;       // act row rt=0
  const size_t r1b = (size_t)(row0 + 16 + li) * HDP;  // act row rt=1

  f32x4 acc2[2][5];
#pragma unroll
  for (int rt = 0; rt < 2; ++rt)
#pragma unroll
    for (int t = 0; t < 5; ++t) acc2[rt][t] = (f32x4){0.f, 0.f, 0.f, 0.f};

#pragma unroll 1
  for (int hf = 0; hf < 2; ++hf) {
    const int ct0 = hf * 20 + cq * 5;
    // ---- phase 1: hidden ctiles [ct0, ct0+5) ----
    f32x4 acc1[2][5];
#pragma unroll
    for (int rt = 0; rt < 2; ++rt)
#pragma unroll
      for (int t = 0; t < 5; ++t) acc1[rt][t] = (f32x4){0.f, 0.f, 0.f, 0.f};
    for (int ks = 0; ks < KS1; ++ks) {
      int k0 = ks * 32 + g * 8;
      short8v a0h = *(const short8v*)(ph + r0b + k0);
      short8v a0l = *(const short8v*)(pl + r0b + k0);
      short8v a1h = *(const short8v*)(ph + r1b + k0);
      short8v a1l = *(const short8v*)(pl + r1b + k0);
      const short8v* whp = (const short8v*)W1hi + ((size_t)ct0 * KS1 + ks) * 64 + lane;
      const short8v* wlp = (const short8v*)W1lo + ((size_t)ct0 * KS1 + ks) * 64 + lane;
#pragma unroll
      for (int ct = 0; ct < 5; ++ct) {
        short8v wh = whp[(size_t)ct * KS1 * 64];
        short8v wl = wlp[(size_t)ct * KS1 * 64];
        acc1[0][ct] = __builtin_amdgcn_mfma_f32_16x16x32_bf16(wh, a0h, acc1[0][ct], 0, 0, 0);
        acc1[0][ct] = __builtin_amdgcn_mfma_f32_16x16x32_bf16(wh, a0l, acc1[0][ct], 0, 0, 0);
        acc1[0][ct] = __builtin_amdgcn_mfma_f32_16x16x32_bf16(wl, a0h, acc1[0][ct], 0, 0, 0);
        acc1[1][ct] = __builtin_amdgcn_mfma_f32_16x16x32_bf16(wh, a1h, acc1[1][ct], 0, 0, 0);
        acc1[1][ct] = __builtin_amdgcn_mfma_f32_16x16x32_bf16(wh, a1l, acc1[1][ct], 0, 0, 0);
        acc1[1][ct] = __builtin_amdgcn_mfma_f32_16x16x32_bf16(wl, a1h, acc1[1][ct], 0, 0, 0);
      }
    }
    if (hf) __syncthreads();  // prior half's phase-2 reads done
    // bias + relu -> split-bf16 LDS (convert once at write)
#pragma unroll
    for (int ct = 0; ct < 5; ++ct) {
      int ctile = ct0 + ct, cc = ctile - hf * 20;
      float bb[4];
#pragma unroll
      for (int q = 0; q < 4; ++q) {
        int c = ctile * 16 + g * 4 + q;
        bb[q] = (c < HD2) ? b1[c] : 0.f;
      }
#pragma unroll
      for (int rt = 0; rt < 2; ++rt) {
        short4v vh, vl;
#pragma unroll
        for (int q = 0; q < 4; ++q) {
          float v = fmaxf(acc1[rt][ct][q] + bb[q], 0.f);
          short hi = f2bf(v);
          vh[q] = hi;
          vl[q] = f2bf(v - bf2f(hi));
        }
        int row = rt * 16 + li;
        int lin = row * 640 + cc * 32 + g * 8;
        int sw = (row & 7) << 4;
        *(short4v*)(hbh + (lin ^ sw)) = vh;
        *(short4v*)(hbl + (lin ^ sw)) = vl;
      }
    }
    __syncthreads();
    // ---- phase 2 partial: ks of this half (pure ds_read + MFMA) ----
    const int nks2 = hf ? 9 : 10;
    for (int ksl = 0; ksl < nks2; ++ksl) {
      int ksg = hf * 10 + ksl;
      int lin0 = li * 640 + ksl * 64 + g * 16;
      int sw0 = (li & 7) << 4;
      int lin1 = (16 + li) * 640 + ksl * 64 + g * 16;
      int sw1 = ((16 + li) & 7) << 4;
      short8v hh0 = *(const short8v*)(hbh + (lin0 ^ sw0));
      short8v hl0 = *(const short8v*)(hbl + (lin0 ^ sw0));
      short8v hh1 = *(const short8v*)(hbh + (lin1 ^ sw1));
      short8v hl1 = *(const short8v*)(hbl + (lin1 ^ sw1));
      const short8v* w2h = (const short8v*)W2hi + ((size_t)(cq * 5) * KS2 + ksg) * 64 + lane;
      const short8v* w2l = (const short8v*)W2lo + ((size_t)(cq * 5) * KS2 + ksg) * 64 + lane;
#pragma unroll
      for (int t = 0; t < 5; ++t) {
        short8v wh = w2h[(size_t)t * KS2 * 64];
        short8v wl = w2l[(size_t)t * KS2 * 64];
        acc2[0][t] = __builtin_amdgcn_mfma_f32_16x16x32_bf16(hh0, wh, acc2[0][t], 0, 0, 0);
        acc2[0][t] = __builtin_amdgcn_mfma_f32_16x16x32_bf16(hl0, wh, acc2[0][t], 0, 0, 0);
        acc2[0][t] = __builtin_amdgcn_mfma_f32_16x16x32_bf16(hh0, wl, acc2[0][t], 0, 0, 0);
        acc2[1][t] = __builtin_amdgcn_mfma_f32_16x16x32_bf16(hh1, wh, acc2[1][t], 0, 0, 0);
        acc2[1][t] = __builtin_amdgcn_mfma_f32_16x16x32_bf16(hl1, wh, acc2[1][t], 0, 0, 0);
        acc2[1][t] = __builtin_amdgcn_mfma_f32_16x16x32_bf16(hh1, wl, acc2[1][t], 0, 0, 0);
      }
    }
  }
  // epilogue: bias, store, fused column stats (guarded for tail rows)
#pragma unroll
  for (int t = 0; t < 5; ++t) {
    int c2 = (cq * 5 + t) * 16 + li;
    if (c2 < HD) {
      float bb = b2[c2];
      float s = 0.f, sq = 0.f;
#pragma unroll
      for (int rt = 0; rt < 2; ++rt) {
#pragma unroll
        for (int q = 0; q < 4; ++q) {
          int gr = row0 + rt * 16 + g * 4 + q;
          if (gr < N) {
            float val = acc2[rt][t][q] + bb;
            out[(size_t)gr * HD + c2] = val;
            s += val;
            sq += val * val;
          }
        }
      }
      s += __shfl_xor(s, 16);  s += __shfl_xor(s, 32);
      sq += __shfl_xor(sq, 16); sq += __shfl_xor(sq, 32);
      if (g == 0) {
        unsafeAtomicAdd(&stats[c2], s);
        unsafeAtomicAdd(&stats[HD + c2], sq);
      }
    }
  }
}

// ---------- generic split-bf16 MFMA GEMM for VN MLP ----------
// BNIN: apply BN(bnst,invM)+relu to A inline.  STATS: fused column stats out.
template <int NKS, int NCTQ, bool BNIN, bool STATS>
__global__ __launch_bounds__(512, 2) void k_gemm_mfma(
    const float* __restrict__ A, const float* __restrict__ A2,
    const float* __restrict__ bnst, const float* __restrict__ bng,
    const float* __restrict__ bnb, float invM,
    const short* __restrict__ Whi, const short* __restrict__ Wlo,
    const float* __restrict__ bias, float* __restrict__ outp,
    float* __restrict__ stats_out, int M, int K, int C) {
  const int tid = threadIdx.x, lane = tid & 63, w = tid >> 6;
  const int rtile = w & 1, cq = w >> 1;
  const int li = lane & 15, g = lane >> 4;
  const int row0 = blockIdx.x * 32;
  const int ct0 = cq * NCTQ;
  const int grow = row0 + rtile * 16 + li;
  const float* arow = A + (size_t)grow * K;
  const float* arow2 = A2 ? A2 + (size_t)grow * K : nullptr;
  f32x4 acc[NCTQ];
#pragma unroll
  for (int t = 0; t < NCTQ; ++t) acc[t] = (f32x4){0.f, 0.f, 0.f, 0.f};
  for (int ks = 0; ks < NKS; ++ks) {
    int k0 = ks * 32 + g * 8;
    short8v fh, fl;
    if (grow < M && k0 + 7 < K) {
      f32x4 q0 = *(const f32x4*)(arow + k0);
      f32x4 q1 = *(const f32x4*)(arow + k0 + 4);
      if (arow2) {
        f32x4 u0 = *(const f32x4*)(arow2 + k0);
        f32x4 u1 = *(const f32x4*)(arow2 + k0 + 4);
#pragma unroll
        for (int j = 0; j < 4; ++j) { q0[j] += u0[j]; q1[j] += u1[j]; }
      }
      if (BNIN) {
        f32x4 s0 = *(const f32x4*)(bnst + k0);
        f32x4 s1 = *(const f32x4*)(bnst + k0 + 4);
        f32x4 q20 = *(const f32x4*)(bnst + K + k0);
        f32x4 q21 = *(const f32x4*)(bnst + K + k0 + 4);
        f32x4 g0 = *(const f32x4*)(bng + k0);
        f32x4 g1 = *(const f32x4*)(bng + k0 + 4);
        f32x4 b0 = *(const f32x4*)(bnb + k0);
        f32x4 b1v = *(const f32x4*)(bnb + k0 + 4);
#pragma unroll
        for (int j = 0; j < 4; ++j) {
          float m = s0[j] * invM, vv = q20[j] * invM - m * m;
          q0[j] = fmaxf(g0[j] * (q0[j] - m) * rsqrtf(vv + 1e-5f) + b0[j], 0.f);
          m = s1[j] * invM; vv = q21[j] * invM - m * m;
          q1[j] = fmaxf(g1[j] * (q1[j] - m) * rsqrtf(vv + 1e-5f) + b1v[j], 0.f);
        }
      }
      cvt8(q0, q1, fh, fl);
    } else {
#pragma unroll
      for (int j = 0; j < 8; ++j) {
        int k = k0 + j;
        float v = 0.f;
        if (grow < M && k < K) {
          v = arow[k];
          if (arow2) v += arow2[k];
          if (BNIN) {
            float m = bnst[k] * invM, vv = bnst[K + k] * invM - m * m;
            v = fmaxf(bng[k] * (v - m) * rsqrtf(vv + 1e-5f) + bnb[k], 0.f);
          }
        }
        short hi = f2bf(v); fh[j] = hi; fl[j] = f2bf(v - bf2f(hi));
      }
    }
    const short8v* whp = (const short8v*)Whi + ((size_t)ct0 * NKS + ks) * 64 + lane;
    const short8v* wlp = (const short8v*)Wlo + ((size_t)ct0 * NKS + ks) * 64 + lane;
#pragma unroll
    for (int t = 0; t < NCTQ; ++t) {
      short8v wh = whp[(size_t)t * NKS * 64];
      short8v wl = wlp[(size_t)t * NKS * 64];
      acc[t] = __builtin_amdgcn_mfma_f32_16x16x32_bf16(fh, wh, acc[t], 0, 0, 0);
      acc[t] = __builtin_amdgcn_mfma_f32_16x16x32_bf16(fl, wh, acc[t], 0, 0, 0);
      acc[t] = __builtin_amdgcn_mfma_f32_16x16x32_bf16(fh, wl, acc[t], 0, 0, 0);
    }
  }
#pragma unroll
  for (int t = 0; t < NCTQ; ++t) {
    int c = (ct0 + t) * 16 + li;
    if (c < C) {
      float bb = bias[c];
      float s = 0.f, sq = 0.f;
#pragma unroll
      for (int q = 0; q < 4; ++q) {
        int gr = row0 + rtile * 16 + g * 4 + q;
        if (gr < M) {
          float val = acc[t][q] + bb;
          outp[(size_t)gr * C + c] = val;
          s += val;
          sq += val * val;
        }
      }
      if (STATS) {
        s += __shfl_xor(s, 16);  s += __shfl_xor(s, 32);
        sq += __shfl_xor(sq, 16); sq += __shfl_xor(sq, 32);
        if (g == 0) {
          unsafeAtomicAdd(&stats_out[c], s);
          unsafeAtomicAdd(&stats_out[C + c], sq);
        }
      }
    }
  }
}

// ---------- graph structure build (once per call) ----------
__global__ __launch_bounds__(256) void k_scatter(const int* __restrict__ dst,
                                                 int* __restrict__ cnt,
                                                 int* __restrict__ bucket,
                                                 int* __restrict__ ovf,
                                                 int* __restrict__ ovf_cnt, int E) {
  int e = blockIdx.x * 256 + threadIdx.x;
  if (e >= E) return;
  int d = dst[e];
  int pos = atomicAdd(&cnt[d], 1);
  if (pos < CAP) bucket[d * CAP + pos] = e;
  else {
    int p2 = atomicAdd(ovf_cnt, 1);
    if (p2 < OVF_MAX) ovf[p2] = e;
  }
}

__global__ __launch_bounds__(256) void k_bounds(const int* __restrict__ batch,
                                                int* __restrict__ start, int N, int B) {
  int n = blockIdx.x * 256 + threadIdx.x;
  if (n >= N) return;
  int b = batch[n];
  int bp = (n == 0) ? -1 : batch[n - 1];
  for (int g = bp + 1; g <= b; ++g) start[g] = n;
  if (n == N - 1)
    for (int g = b + 1; g <= B; ++g) start[g] = N;
}

// ---------- aggregation (f32x4): pre(split) = h[n]+vn[bn] + sum relu(h[s]+vn[bs]+bond) ----------
__global__ __launch_bounds__(256) void k_aggr(const float* __restrict__ h,
                                              const float* __restrict__ vn,
                                              const float* __restrict__ bond,
                                              const int* __restrict__ batch,
                                              const int* __restrict__ src,
                                              const int* __restrict__ dst,
                                              const int* __restrict__ ea,
                                              const int* __restrict__ bucket,
                                              const int* __restrict__ cnt,
                                              const int* __restrict__ ovf,
                                              const int* __restrict__ ovfc,
                                              unsigned short* __restrict__ ph,
                                              unsigned short* __restrict__ pl, int N) {
  int n = (blockIdx.x * 256 + threadIdx.x) >> 6;
  int lane = threadIdx.x & 63;
  if (n >= N) return;
  int bn = batch[n];
  const bool l2 = lane < 11;           // vec idx 64+lane < 75
  const int i0 = lane * 4, i1 = (64 + lane) * 4;  // float offsets
  f32x4 acc0, acc1;
  {
    f32x4 a = *(const f32x4*)(h + (size_t)n * HD + i0);
    f32x4 b = *(const f32x4*)(vn + (size_t)bn * HD + i0);
#pragma unroll
    for (int q = 0; q < 4; ++q) acc0[q] = a[q] + b[q];
  }
  if (l2) {
    f32x4 a = *(const f32x4*)(h + (size_t)n * HD + i1);
    f32x4 b = *(const f32x4*)(vn + (size_t)bn * HD + i1);
#pragma unroll
    for (int q = 0; q < 4; ++q) acc1[q] = a[q] + b[q];
  } else {
#pragma unroll
    for (int q = 0; q < 4; ++q) acc1[q] = 0.f;
  }
  int c = cnt[n];
  int cb = min(c, CAP);
  for (int i = 0; i < cb; ++i) {
    int e = bucket[n * CAP + i];
    int s = src[e], a = ea[e], bs = batch[s];
    const float* hs = h + (size_t)s * HD;
    const float* vs = vn + (size_t)bs * HD;
    const float* bb = bond + (size_t)a * HD;
    f32x4 hv = *(const f32x4*)(hs + i0);
    f32x4 vv = *(const f32x4*)(vs + i0);
    f32x4 bv = *(const f32x4*)(bb + i0);
#pragma unroll
    for (int q = 0; q < 4; ++q) acc0[q] += fmaxf(hv[q] + vv[q] + bv[q], 0.f);
    if (l2) {
      hv = *(const f32x4*)(hs + i1);
      vv = *(const f32x4*)(vs + i1);
      bv = *(const f32x4*)(bb + i1);
#pragma unroll
      for (int q = 0; q < 4; ++q) acc1[q] += fmaxf(hv[q] + vv[q] + bv[q], 0.f);
    }
  }
  if (c > CAP) {  // rare: scan small overflow list
    int nov = min(*ovfc, OVF_MAX);
    for (int i = 0; i < nov; ++i) {
      int e = ovf[i];
      if (dst[e] != n) continue;
      int s = src[e], a = ea[e], bs = batch[s];
      const float* hs = h + (size_t)s * HD;
      const float* vs = vn + (size_t)bs * HD;
      const float* bb = bond + (size_t)a * HD;
      f32x4 hv = *(const f32x4*)(hs + i0);
      f32x4 vv = *(const f32x4*)(vs + i0);
      f32x4 bv = *(const f32x4*)(bb + i0);
#pragma unroll
      for (int q = 0; q < 4; ++q) acc0[q] += fmaxf(hv[q] + vv[q] + bv[q], 0.f);
      if (l2) {
        hv = *(const f32x4*)(hs + i1);
        vv = *(const f32x4*)(vs + i1);
        bv = *(const f32x4*)(bb + i1);
#pragma unroll
        for (int q = 0; q < 4; ++q) acc1[q] += fmaxf(hv[q] + vv[q] + bv[q], 0.f);
      }
    }
  }
  unsigned short* phr = ph + (size_t)n * HDP;
  unsigned short* plr = pl + (size_t)n * HDP;
  short4v h0, l0;
#pragma unroll
  for (int q = 0; q < 4; ++q) {
    short hi = f2bf(acc0[q]); h0[q] = hi; l0[q] = f2bf(acc0[q] - bf2f(hi));
  }
  *(short4v*)(phr + i0) = h0;
  *(short4v*)(plr + i0) = l0;
  if (lane < 12) {  // lanes 0..10 = data; lane 11 = zero pad (shorts 300..303)
    short4v h1, l1;
    if (l2) {
#pragma unroll
      for (int q = 0; q < 4; ++q) {
        short hi = f2bf(acc1[q]); h1[q] = hi; l1[q] = f2bf(acc1[q] - bf2f(hi));
      }
    } else {
#pragma unroll
      for (int q = 0; q < 4; ++q) { h1[q] = 0; l1[q] = 0; }
    }
    *(short4v*)(phr + i1) = h1;
    *(short4v*)(plr + i1) = l1;
  }
}

// ---------- fused BN apply + segment pooling (f32x4, one block per graph) ----------
__global__ __launch_bounds__(64) void k_bn_pool(const float* __restrict__ x,
                                                const float* __restrict__ gw,
                                                const float* __restrict__ bw,
                                                const float* __restrict__ stats,
                                                float invM,
                                                const int* __restrict__ start,
                                                int relu, float* __restrict__ hout,
                                                float* __restrict__ pooled) {
  int grf = blockIdx.x, lane = threadIdx.x;
  int r0 = start[grf], r1 = start[grf + 1];
  const bool l2 = lane < 11;
  const int i0 = lane * 4, i1 = (64 + lane) * 4;
  f32x4 m0, rs0, g0, b0, m1, rs1, g1, b1, acc0, acc1;
  {
    f32x4 s = *(const f32x4*)(stats + i0);
    f32x4 q = *(const f32x4*)(stats + HD + i0);
    g0 = *(const f32x4*)(gw + i0);
    b0 = *(const f32x4*)(bw + i0);
#pragma unroll
    for (int j = 0; j < 4; ++j) {
      float mm = s[j] * invM;
      float vv = q[j] * invM - mm * mm;
      m0[j] = mm; rs0[j] = rsqrtf(vv + 1e-5f);
      acc0[j] = 0.f;
    }
  }
  if (l2) {
    f32x4 s = *(const f32x4*)(stats + i1);
    f32x4 q = *(const f32x4*)(stats + HD + i1);
    g1 = *(const f32x4*)(gw + i1);
    b1 = *(const f32x4*)(bw + i1);
#pragma unroll
    for (int j = 0; j < 4; ++j) {
      float mm = s[j] * invM;
      float vv = q[j] * invM - mm * mm;
      m1[j] = mm; rs1[j] = rsqrtf(vv + 1e-5f);
      acc1[j] = 0.f;
    }
  }
  for (int r = r0; r < r1; ++r) {
    const float* xr = x + (size_t)r * HD;
    f32x4 v = *(const f32x4*)(xr + i0);
#pragma unroll
    for (int j = 0; j < 4; ++j) {
      float val = g0[j] * (v[j] - m0[j]) * rs0[j] + b0[j];
      if (relu) val = fmaxf(val, 0.f);
      v[j] = val;
      acc0[j] += val;
    }
    if (hout) *(f32x4*)(hout + (size_t)r * HD + i0) = v;
    if (l2) {
      f32x4 v2 = *(const f32x4*)(xr + i1);
#pragma unroll
      for (int j = 0; j < 4; ++j) {
        float val = g1[j] * (v2[j] - m1[j]) * rs1[j] + b1[j];
        if (relu) val = fmaxf(val, 0.f);
        v2[j] = val;
        acc1[j] += val;
      }
      if (hout) *(f32x4*)(hout + (size_t)r * HD + i1) = v2;
    }
  }
  float* op = pooled + (size_t)grf * HD;
  *(f32x4*)(op + i0) = acc0;
  if (l2) *(f32x4*)(op + i1) = acc1;
}

// plain BN apply (vt2 -> vn)
__global__ __launch_bounds__(256) void k_bn_apply(const float* __restrict__ x,
                                                  const float* __restrict__ g,
                                                  const float* __restrict__ b,
                                                  const float* __restrict__ stats,
                                                  float invM, int C, int total, int relu,
                                                  float* __restrict__ out) {
  int idx = blockIdx.x * 256 + threadIdx.x;
  if (idx >= total) return;
  int n = idx / C, c = idx - n * C;
  float m = stats[c] * invM;
  float v = stats[C + c] * invM - m * m;
  float val = g[c] * (x[idx] - m) * rsqrtf(v + 1e-5f) + b[c];
  if (relu) val = fmaxf(val, 0.f);
  out[idx] = val;
}

// ---------- init ----------
__global__ __launch_bounds__(256) void k_init_h(const int* __restrict__ x,
                                                const float* __restrict__ emb,
                                                float* __restrict__ h, int nvec) {
  int idx = blockIdx.x * 256 + threadIdx.x;
  if (idx >= nvec) return;
  int n = idx / 75, c4 = idx - n * 75;
  ((float4*)h)[idx] = *(const float4*)(emb + (size_t)x[n] * HD + c4 * 4);
}

__global__ __launch_bounds__(256) void k_init_vn(const float* __restrict__ vn_emb,
                                                 float* __restrict__ vn, int total) {
  int idx = blockIdx.x * 256 + threadIdx.x;
  if (idx >= total) return;
  vn[idx] = vn_emb[idx % HD];
}

extern "C" void kernel_launch(void* const* d_in, const int* in_sizes, int n_in,
                              void* d_out, int out_size, void* d_ws, size_t ws_size,
                              hipStream_t stream) {
  const int N = in_sizes[0];        // 100000
  const int E = in_sizes[2];        // 200000
  const int B = out_size / HD;      // 4096

  const int* x     = (const int*)d_in[0];
  const int* src   = (const int*)d_in[1];
  const int* dst   = src + E;
  const int* ea    = (const int*)d_in[2];
  const int* batch = (const int*)d_in[3];
  const float* atom_emb = (const float*)d_in[5];
  const float* bond_emb = (const float*)d_in[6];
  const float* vn_emb   = (const float*)d_in[7];
  const float* W1   = (const float*)d_in[8];
  const float* b1   = (const float*)d_in[9];
  const float* W2   = (const float*)d_in[10];
  const float* b2   = (const float*)d_in[11];
  const float* bn_g = (const float*)d_in[12];
  const float* bn_b = (const float*)d_in[13];
  const float* vW1  = (const float*)d_in[14];
  const float* vb1  = (const float*)d_in[15];
  const float* vg1  = (const float*)d_in[16];
  const float* vbb1 = (const float*)d_in[17];
  const float* vW2  = (const float*)d_in[18];
  const float* vb2  = (const float*)d_in[19];
  const float* vg2  = (const float*)d_in[20];
  const float* vbb2 = (const float*)d_in[21];

  const size_t NH = (size_t)N * HD;
  const size_t BH = (size_t)B * HD;
  const size_t T1 = (size_t)CT1P * KS1 * 512;  // 204,800 shorts
  const size_t T2 = (size_t)CT2P * KS2 * 512;  // 194,560 shorts
  const size_t NPAD = (size_t)N + 64;          // ph/pl row padding (tail safety)

  // ---- workspace layout ----
  char* base = (char*)d_ws;
  size_t off = 0;
  float* h     = (float*)(base + off); off += NH * 4;
  unsigned short* ph = (unsigned short*)(base + off); off += NPAD * HDP * 2;
  unsigned short* pl = (unsigned short*)(base + off); off += NPAD * HDP * 2;
  float* vn    = (float*)(base + off); off += BH * 4;
  float* vt1   = (float*)(base + off); off += (size_t)B * HD2 * 4;
  float* pool  = (float*)(base + off); off += BH * 4;   // aliased as vt2
  float* vt2   = pool;
  float* stats = (float*)(base + off); off += 12000 * 4;
  int* cnt     = (int*)(base + off); off += (size_t)N * 4;
  int* ovfc    = (int*)(base + off); off += 4;
  int* ovf     = (int*)(base + off); off += (size_t)OVF_MAX * 4;
  int* start   = (int*)(base + off); off += (size_t)(B + 1) * 4;
  int* bucket  = (int*)(base + off); off += (size_t)N * CAP * 4;
  off = (off + 15) & ~(size_t)15;
  short* Ahi   = (short*)(base + off); off += T1 * 2;
  short* Alo   = (short*)(base + off); off += T1 * 2;
  short* Bhi   = (short*)(base + off); off += T2 * 2;
  short* Blo   = (short*)(base + off); off += T2 * 2;
  const size_t need_base = off;
  // optional dedicated VN frag buffers (prep once instead of per layer)
  short* vAhi = (short*)(base + off); off += T1 * 2;
  short* vAlo = (short*)(base + off); off += T1 * 2;
  short* vBhi = (short*)(base + off); off += T2 * 2;
  short* vBlo = (short*)(base + off); off += T2 * 2;
  const size_t need_full = off;
  const bool hoist_vw = (ws_size >= need_full);
  if (ws_size < need_base) {  // diagnostic fallback
    hipMemsetAsync(d_out, 0, (size_t)out_size * sizeof(float), stream);
    return;
  }
  if (!hoist_vw) { vAhi = Ahi; vAlo = Alo; vBhi = Bhi; vBlo = Blo; }

  // stats | cnt | ovfc are contiguous -> single memset
  hipMemsetAsync(stats, 0, 12000 * sizeof(float) + ((size_t)N + 1) * sizeof(int), stream);

  k_scatter<<<(E + 255) / 256, 256, 0, stream>>>(dst, cnt, bucket, ovf, ovfc, E);
  k_bounds<<<(N + 255) / 256, 256, 0, stream>>>(batch, start, N, B);

  const int totBH = (int)BH;
  const int nvNH = (int)NH / 4;
  const int t1 = (int)T1, t2 = (int)T2;
  k_init_h<<<(nvNH + 255) / 256, 256, 0, stream>>>(x, atom_emb, h, nvNH);
  k_init_vn<<<(totBH + 255) / 256, 256, 0, stream>>>(vn_emb, vn, totBH);
  if (hoist_vw) {
    k_prep_wf<<<(t1 + 255) / 256, 256, 0, stream>>>(vW1, vAhi, vAlo, HD, HD2, KS1, t1);
    k_prep_wf<<<(t2 + 255) / 256, 256, 0, stream>>>(vW2, vBhi, vBlo, HD2, HD, KS2, t2);
  }

  for (int i = 0; i < NLAYER; ++i) {
    float* stL  = stats + i * 2400;
    float* stV1 = stL + 2 * HD;
    float* stV2 = stV1 + 2 * HD2;
    const int last = (i == NLAYER - 1);
    float* pool_i = last ? (float*)d_out : pool;

    k_prep_wf<<<(t1 + 255) / 256, 256, 0, stream>>>(
        W1 + (size_t)i * HD * HD2, Ahi, Alo, HD, HD2, KS1, t1);
    k_prep_wf<<<(t2 + 255) / 256, 256, 0, stream>>>(
        W2 + (size_t)i * HD2 * HD, Bhi, Blo, HD2, HD, KS2, t2);

    k_aggr<<<(N * 64 + 255) / 256, 256, 0, stream>>>(
        h, vn, bond_emb, batch, src, dst, ea, bucket, cnt, ovf, ovfc, ph, pl, N);
    k_mlp_mfma<<<(N + 31) / 32, 256, 0, stream>>>(
        ph, pl, Ahi, Alo, b1 + (size_t)i * HD2, Bhi, Blo, b2 + (size_t)i * HD,
        h, stL, N);
    k_bn_pool<<<B, 64, 0, stream>>>(h, bn_g + i * HD, bn_b + i * HD, stL,
                                    1.f / (float)N, start, last ? 0 : 1,
                                    last ? nullptr : h, pool_i);

    if (!last) {
      if (!hoist_vw) {
        k_prep_wf<<<(t1 + 255) / 256, 256, 0, stream>>>(vW1, vAhi, vAlo, HD, HD2, KS1, t1);
      }
      k_gemm_mfma<KS1, 10, false, true><<<B / 32, 512, 0, stream>>>(
          pool, vn, nullptr, nullptr, nullptr, 0.f, vAhi, vAlo, vb1, vt1, stV1, B, HD, HD2);
      if (!hoist_vw) {
        k_prep_wf<<<(t2 + 255) / 256, 256, 0, stream>>>(vW2, vBhi, vBlo, HD2, HD, KS2, t2);
      }
      k_gemm_mfma<KS2, 5, true, true><<<B / 32, 512, 0, stream>>>(
          vt1, nullptr, stV1, vg1, vbb1, 1.f / (float)B, vBhi, vBlo, vb2, vt2, stV2, B, HD2, HD);
      k_bn_apply<<<(totBH + 255) / 256, 256, 0, stream>>>(
          vt2, vg2, vbb2, stV2, 1.f / (float)B, HD, totBH, 1, vn);
    }
  }
}

// Round 17
// 3549.972 us; speedup vs baseline: 1.7400x; 1.0040x over previous
//
#include <hip/hip_runtime.h>
#include <hip/hip_bf16.h>

// vGINMolEncoder: 5-layer GINE + virtual node, H=300, f32 in/out.
// Round 17: r16 + ILP in the MLP k-loops (#pragma unroll 2) — exposes 2
// iterations of weight loads to the scheduler. Live set ~120 VGPR < the
// (256,3) cap of 170 (no spill possible); LDS remains the occupancy cap so
// the VGPR rise costs nothing. Everything else identical to r16 (3.56 ms).
// Split-bf16 (hi+lo) MFMA, f32 accum.

#define HD 300
#define HD2 600
#define HDP 304   // padded pre row (shorts)
#define NLAYER 5
#define KS1 10   // 320/32
#define KS2 19   // 608/32
#define CT1P 40  // padded hidden col tiles (38 real)
#define CT2P 20  // padded out col tiles (19 real)
#define CAP 8
#define OVF_MAX 8192

typedef __attribute__((ext_vector_type(8))) short short8v;
typedef __attribute__((ext_vector_type(4))) short short4v;
typedef __attribute__((ext_vector_type(4))) float f32x4;

__device__ __forceinline__ short f2bf(float x) {  // RNE f32->bf16
  union { float f; unsigned u; } v; v.f = x;
  unsigned r = v.u + 0x7fffu + ((v.u >> 16) & 1u);
  return (short)(r >> 16);
}
__device__ __forceinline__ float bf2f(short h) {
  union { unsigned u; float f; } v; v.u = ((unsigned)(unsigned short)h) << 16;
  return v.f;
}

__device__ __forceinline__ void cvt8(f32x4 x0, f32x4 x1, short8v& fh, short8v& fl) {
#pragma unroll
  for (int j = 0; j < 4; ++j) { short hi = f2bf(x0[j]); fh[j] = hi; fl[j] = f2bf(x0[j] - bf2f(hi)); }
#pragma unroll
  for (int j = 0; j < 4; ++j) { short hi = f2bf(x1[j]); fh[4 + j] = hi; fl[4 + j] = f2bf(x1[j] - bf2f(hi)); }
}

// ---------- weight repack to hi/lo fragment order ----------
__global__ __launch_bounds__(256) void k_prep_wf(const float* __restrict__ W,
                                                 short* __restrict__ Whi,
                                                 short* __restrict__ Wlo,
                                                 int K, int C, int nks, int total) {
  int idx = blockIdx.x * 256 + threadIdx.x;
  if (idx >= total) return;
  int j = idx & 7, lane = (idx >> 3) & 63, t = idx >> 9;
  int ks = t % nks, ct = t / nks;
  int k = ks * 32 + (lane >> 4) * 8 + j;
  int c = ct * 16 + (lane & 15);
  float w = (k < K && c < C) ? W[(size_t)k * C + c] : 0.f;
  short hi = f2bf(w);
  Whi[idx] = hi;
  Wlo[idx] = f2bf(w - bf2f(hi));
}

// ---------- fused node MLP + BN-stats (proven 32-row, 4-wave structure) ----------
__global__ __launch_bounds__(256, 3) void k_mlp_mfma(
    const unsigned short* __restrict__ ph, const unsigned short* __restrict__ pl,
    const short* __restrict__ W1hi, const short* __restrict__ W1lo,
    const float* __restrict__ b1,
    const short* __restrict__ W2hi, const short* __restrict__ W2lo,
    const float* __restrict__ b2, float* __restrict__ out,
    float* __restrict__ stats, int N) {
  __shared__ __align__(16) short hidh[32 * 320];  // 20,480 B
  __shared__ __align__(16) short hidl[32 * 320];  // 20,480 B
  char* hbh = (char*)hidh;
  char* hbl = (char*)hidl;
  const int tid = threadIdx.x;
  const int lane = tid & 63, cq = tid >> 6;   // 4 waves = 4 col-quarters
  const int li = lane & 15, g = lane >> 4;
  const int row0 = blockIdx.x * 32;
  const size_t r0b = (size_t)(row0 + li) * HDP;       // act row rt=0
  const size_t r1b = (size_t)(row0 + 16 + li) * HDP;  // act row rt=1

  f32x4 acc2[2][5];
#pragma unroll
  for (int rt = 0; rt < 2; ++rt)
#pragma unroll
    for (int t = 0; t < 5; ++t) acc2[rt][t] = (f32x4){0.f, 0.f, 0.f, 0.f};

#pragma unroll 1
  for (int hf = 0; hf < 2; ++hf) {
    const int ct0 = hf * 20 + cq * 5;
    // ---- phase 1: hidden ctiles [ct0, ct0+5) ----
    f32x4 acc1[2][5];
#pragma unroll
    for (int rt = 0; rt < 2; ++rt)
#pragma unroll
      for (int t = 0; t < 5; ++t) acc1[rt][t] = (f32x4){0.f, 0.f, 0.f, 0.f};
#pragma unroll 2
    for (int ks = 0; ks < KS1; ++ks) {
      int k0 = ks * 32 + g * 8;
      short8v a0h = *(const short8v*)(ph + r0b + k0);
      short8v a0l = *(const short8v*)(pl + r0b + k0);
      short8v a1h = *(const short8v*)(ph + r1b + k0);
      short8v a1l = *(const short8v*)(pl + r1b + k0);
      const short8v* whp = (const short8v*)W1hi + ((size_t)ct0 * KS1 + ks) * 64 + lane;
      const short8v* wlp = (const short8v*)W1lo + ((size_t)ct0 * KS1 + ks) * 64 + lane;
#pragma unroll
      for (int ct = 0; ct < 5; ++ct) {
        short8v wh = whp[(size_t)ct * KS1 * 64];
        short8v wl = wlp[(size_t)ct * KS1 * 64];
        acc1[0][ct] = __builtin_amdgcn_mfma_f32_16x16x32_bf16(wh, a0h, acc1[0][ct], 0, 0, 0);
        acc1[0][ct] = __builtin_amdgcn_mfma_f32_16x16x32_bf16(wh, a0l, acc1[0][ct], 0, 0, 0);
        acc1[0][ct] = __builtin_amdgcn_mfma_f32_16x16x32_bf16(wl, a0h, acc1[0][ct], 0, 0, 0);
        acc1[1][ct] = __builtin_amdgcn_mfma_f32_16x16x32_bf16(wh, a1h, acc1[1][ct], 0, 0, 0);
        acc1[1][ct] = __builtin_amdgcn_mfma_f32_16x16x32_bf16(wh, a1l, acc1[1][ct], 0, 0, 0);
        acc1[1][ct] = __builtin_amdgcn_mfma_f32_16x16x32_bf16(wl, a1h, acc1[1][ct], 0, 0, 0);
      }
    }
    if (hf) __syncthreads();  // prior half's phase-2 reads done
    // bias + relu -> split-bf16 LDS (convert once at write)
#pragma unroll
    for (int ct = 0; ct < 5; ++ct) {
      int ctile = ct0 + ct, cc = ctile - hf * 20;
      float bb[4];
#pragma unroll
      for (int q = 0; q < 4; ++q) {
        int c = ctile * 16 + g * 4 + q;
        bb[q] = (c < HD2) ? b1[c] : 0.f;
      }
#pragma unroll
      for (int rt = 0; rt < 2; ++rt) {
        short4v vh, vl;
#pragma unroll
        for (int q = 0; q < 4; ++q) {
          float v = fmaxf(acc1[rt][ct][q] + bb[q], 0.f);
          short hi = f2bf(v);
          vh[q] = hi;
          vl[q] = f2bf(v - bf2f(hi));
        }
        int row = rt * 16 + li;
        int lin = row * 640 + cc * 32 + g * 8;
        int sw = (row & 7) << 4;
        *(short4v*)(hbh + (lin ^ sw)) = vh;
        *(short4v*)(hbl + (lin ^ sw)) = vl;
      }
    }
    __syncthreads();
    // ---- phase 2 partial: ks of this half (pure ds_read + MFMA) ----
    const int nks2 = hf ? 9 : 10;
#pragma unroll 2
    for (int ksl = 0; ksl < nks2; ++ksl) {
      int ksg = hf * 10 + ksl;
      int lin0 = li * 640 + ksl * 64 + g * 16;
      int sw0 = (li & 7) << 4;
      int lin1 = (16 + li) * 640 + ksl * 64 + g * 16;
      int sw1 = ((16 + li) & 7) << 4;
      short8v hh0 = *(const short8v*)(hbh + (lin0 ^ sw0));
      short8v hl0 = *(const short8v*)(hbl + (lin0 ^ sw0));
      short8v hh1 = *(const short8v*)(hbh + (lin1 ^ sw1));
      short8v hl1 = *(const short8v*)(hbl + (lin1 ^ sw1));
      const short8v* w2h = (const short8v*)W2hi + ((size_t)(cq * 5) * KS2 + ksg) * 64 + lane;
      const short8v* w2l = (const short8v*)W2lo + ((size_t)(cq * 5) * KS2 + ksg) * 64 + lane;
#pragma unroll
      for (int t = 0; t < 5; ++t) {
        short8v wh = w2h[(size_t)t * KS2 * 64];
        short8v wl = w2l[(size_t)t * KS2 * 64];
        acc2[0][t] = __builtin_amdgcn_mfma_f32_16x16x32_bf16(hh0, wh, acc2[0][t], 0, 0, 0);
        acc2[0][t] = __builtin_amdgcn_mfma_f32_16x16x32_bf16(hl0, wh, acc2[0][t], 0, 0, 0);
        acc2[0][t] = __builtin_amdgcn_mfma_f32_16x16x32_bf16(hh0, wl, acc2[0][t], 0, 0, 0);
        acc2[1][t] = __builtin_amdgcn_mfma_f32_16x16x32_bf16(hh1, wh, acc2[1][t], 0, 0, 0);
        acc2[1][t] = __builtin_amdgcn_mfma_f32_16x16x32_bf16(hl1, wh, acc2[1][t], 0, 0, 0);
        acc2[1][t] = __builtin_amdgcn_mfma_f32_16x16x32_bf16(hh1, wl, acc2[1][t], 0, 0, 0);
      }
    }
  }
  // epilogue: bias, store, fused column stats (guarded for tail rows)
#pragma unroll
  for (int t = 0; t < 5; ++t) {
    int c2 = (cq * 5 + t) * 16 + li;
    if (c2 < HD) {
      float bb = b2[c2];
      float s = 0.f, sq = 0.f;
#pragma unroll
      for (int rt = 0; rt < 2; ++rt) {
#pragma unroll
        for (int q = 0; q < 4; ++q) {
          int gr = row0 + rt * 16 + g * 4 + q;
          if (gr < N) {
            float val = acc2[rt][t][q] + bb;
            out[(size_t)gr * HD + c2] = val;
            s += val;
            sq += val * val;
          }
        }
      }
      s += __shfl_xor(s, 16);  s += __shfl_xor(s, 32);
      sq += __shfl_xor(sq, 16); sq += __shfl_xor(sq, 32);
      if (g == 0) {
        unsafeAtomicAdd(&stats[c2], s);
        unsafeAtomicAdd(&stats[HD + c2], sq);
      }
    }
  }
}

// ---------- generic split-bf16 MFMA GEMM for VN MLP ----------
// BNIN: apply BN(bnst,invM)+relu to A inline.  STATS: fused column stats out.
template <int NKS, int NCTQ, bool BNIN, bool STATS>
__global__ __launch_bounds__(512, 2) void k_gemm_mfma(
    const float* __restrict__ A, const float* __restrict__ A2,
    const float* __restrict__ bnst, const float* __restrict__ bng,
    const float* __restrict__ bnb, float invM,
    const short* __restrict__ Whi, const short* __restrict__ Wlo,
    const float* __restrict__ bias, float* __restrict__ outp,
    float* __restrict__ stats_out, int M, int K, int C) {
  const int tid = threadIdx.x, lane = tid & 63, w = tid >> 6;
  const int rtile = w & 1, cq = w >> 1;
  const int li = lane & 15, g = lane >> 4;
  const int row0 = blockIdx.x * 32;
  const int ct0 = cq * NCTQ;
  const int grow = row0 + rtile * 16 + li;
  const float* arow = A + (size_t)grow * K;
  const float* arow2 = A2 ? A2 + (size_t)grow * K : nullptr;
  f32x4 acc[NCTQ];
#pragma unroll
  for (int t = 0; t < NCTQ; ++t) acc[t] = (f32x4){0.f, 0.f, 0.f, 0.f};
  for (int ks = 0; ks < NKS; ++ks) {
    int k0 = ks * 32 + g * 8;
    short8v fh, fl;
    if (grow < M && k0 + 7 < K) {
      f32x4 q0 = *(const f32x4*)(arow + k0);
      f32x4 q1 = *(const f32x4*)(arow + k0 + 4);
      if (arow2) {
        f32x4 u0 = *(const f32x4*)(arow2 + k0);
        f32x4 u1 = *(const f32x4*)(arow2 + k0 + 4);
#pragma unroll
        for (int j = 0; j < 4; ++j) { q0[j] += u0[j]; q1[j] += u1[j]; }
      }
      if (BNIN) {
        f32x4 s0 = *(const f32x4*)(bnst + k0);
        f32x4 s1 = *(const f32x4*)(bnst + k0 + 4);
        f32x4 q20 = *(const f32x4*)(bnst + K + k0);
        f32x4 q21 = *(const f32x4*)(bnst + K + k0 + 4);
        f32x4 g0 = *(const f32x4*)(bng + k0);
        f32x4 g1 = *(const f32x4*)(bng + k0 + 4);
        f32x4 b0 = *(const f32x4*)(bnb + k0);
        f32x4 b1v = *(const f32x4*)(bnb + k0 + 4);
#pragma unroll
        for (int j = 0; j < 4; ++j) {
          float m = s0[j] * invM, vv = q20[j] * invM - m * m;
          q0[j] = fmaxf(g0[j] * (q0[j] - m) * rsqrtf(vv + 1e-5f) + b0[j], 0.f);
          m = s1[j] * invM; vv = q21[j] * invM - m * m;
          q1[j] = fmaxf(g1[j] * (q1[j] - m) * rsqrtf(vv + 1e-5f) + b1v[j], 0.f);
        }
      }
      cvt8(q0, q1, fh, fl);
    } else {
#pragma unroll
      for (int j = 0; j < 8; ++j) {
        int k = k0 + j;
        float v = 0.f;
        if (grow < M && k < K) {
          v = arow[k];
          if (arow2) v += arow2[k];
          if (BNIN) {
            float m = bnst[k] * invM, vv = bnst[K + k] * invM - m * m;
            v = fmaxf(bng[k] * (v - m) * rsqrtf(vv + 1e-5f) + bnb[k], 0.f);
          }
        }
        short hi = f2bf(v); fh[j] = hi; fl[j] = f2bf(v - bf2f(hi));
      }
    }
    const short8v* whp = (const short8v*)Whi + ((size_t)ct0 * NKS + ks) * 64 + lane;
    const short8v* wlp = (const short8v*)Wlo + ((size_t)ct0 * NKS + ks) * 64 + lane;
#pragma unroll
    for (int t = 0; t < NCTQ; ++t) {
      short8v wh = whp[(size_t)t * NKS * 64];
      short8v wl = wlp[(size_t)t * NKS * 64];
      acc[t] = __builtin_amdgcn_mfma_f32_16x16x32_bf16(fh, wh, acc[t], 0, 0, 0);
      acc[t] = __builtin_amdgcn_mfma_f32_16x16x32_bf16(fl, wh, acc[t], 0, 0, 0);
      acc[t] = __builtin_amdgcn_mfma_f32_16x16x32_bf16(fh, wl, acc[t], 0, 0, 0);
    }
  }
#pragma unroll
  for (int t = 0; t < NCTQ; ++t) {
    int c = (ct0 + t) * 16 + li;
    if (c < C) {
      float bb = bias[c];
      float s = 0.f, sq = 0.f;
#pragma unroll
      for (int q = 0; q < 4; ++q) {
        int gr = row0 + rtile * 16 + g * 4 + q;
        if (gr < M) {
          float val = acc[t][q] + bb;
          outp[(size_t)gr * C + c] = val;
          s += val;
          sq += val * val;
        }
      }
      if (STATS) {
        s += __shfl_xor(s, 16);  s += __shfl_xor(s, 32);
        sq += __shfl_xor(sq, 16); sq += __shfl_xor(sq, 32);
        if (g == 0) {
          unsafeAtomicAdd(&stats_out[c], s);
          unsafeAtomicAdd(&stats_out[C + c], sq);
        }
      }
    }
  }
}

// ---------- graph structure build (once per call) ----------
__global__ __launch_bounds__(256) void k_scatter(const int* __restrict__ dst,
                                                 int* __restrict__ cnt,
                                                 int* __restrict__ bucket,
                                                 int* __restrict__ ovf,
                                                 int* __restrict__ ovf_cnt, int E) {
  int e = blockIdx.x * 256 + threadIdx.x;
  if (e >= E) return;
  int d = dst[e];
  int pos = atomicAdd(&cnt[d], 1);
  if (pos < CAP) bucket[d * CAP + pos] = e;
  else {
    int p2 = atomicAdd(ovf_cnt, 1);
    if (p2 < OVF_MAX) ovf[p2] = e;
  }
}

__global__ __launch_bounds__(256) void k_bounds(const int* __restrict__ batch,
                                                int* __restrict__ start, int N, int B) {
  int n = blockIdx.x * 256 + threadIdx.x;
  if (n >= N) return;
  int b = batch[n];
  int bp = (n == 0) ? -1 : batch[n - 1];
  for (int g = bp + 1; g <= b; ++g) start[g] = n;
  if (n == N - 1)
    for (int g = b + 1; g <= B; ++g) start[g] = N;
}

// ---------- aggregation (f32x4): pre(split) = h[n]+vn[bn] + sum relu(h[s]+vn[bs]+bond) ----------
__global__ __launch_bounds__(256) void k_aggr(const float* __restrict__ h,
                                              const float* __restrict__ vn,
                                              const float* __restrict__ bond,
                                              const int* __restrict__ batch,
                                              const int* __restrict__ src,
                                              const int* __restrict__ dst,
                                              const int* __restrict__ ea,
                                              const int* __restrict__ bucket,
                                              const int* __restrict__ cnt,
                                              const int* __restrict__ ovf,
                                              const int* __restrict__ ovfc,
                                              unsigned short* __restrict__ ph,
                                              unsigned short* __restrict__ pl, int N) {
  int n = (blockIdx.x * 256 + threadIdx.x) >> 6;
  int lane = threadIdx.x & 63;
  if (n >= N) return;
  int bn = batch[n];
  const bool l2 = lane < 11;           // vec idx 64+lane < 75
  const int i0 = lane * 4, i1 = (64 + lane) * 4;  // float offsets
  f32x4 acc0, acc1;
  {
    f32x4 a = *(const f32x4*)(h + (size_t)n * HD + i0);
    f32x4 b = *(const f32x4*)(vn + (size_t)bn * HD + i0);
#pragma unroll
    for (int q = 0; q < 4; ++q) acc0[q] = a[q] + b[q];
  }
  if (l2) {
    f32x4 a = *(const f32x4*)(h + (size_t)n * HD + i1);
    f32x4 b = *(const f32x4*)(vn + (size_t)bn * HD + i1);
#pragma unroll
    for (int q = 0; q < 4; ++q) acc1[q] = a[q] + b[q];
  } else {
#pragma unroll
    for (int q = 0; q < 4; ++q) acc1[q] = 0.f;
  }
  int c = cnt[n];
  int cb = min(c, CAP);
  for (int i = 0; i < cb; ++i) {
    int e = bucket[n * CAP + i];
    int s = src[e], a = ea[e], bs = batch[s];
    const float* hs = h + (size_t)s * HD;
    const float* vs = vn + (size_t)bs * HD;
    const float* bb = bond + (size_t)a * HD;
    f32x4 hv = *(const f32x4*)(hs + i0);
    f32x4 vv = *(const f32x4*)(vs + i0);
    f32x4 bv = *(const f32x4*)(bb + i0);
#pragma unroll
    for (int q = 0; q < 4; ++q) acc0[q] += fmaxf(hv[q] + vv[q] + bv[q], 0.f);
    if (l2) {
      hv = *(const f32x4*)(hs + i1);
      vv = *(const f32x4*)(vs + i1);
      bv = *(const f32x4*)(bb + i1);
#pragma unroll
      for (int q = 0; q < 4; ++q) acc1[q] += fmaxf(hv[q] + vv[q] + bv[q], 0.f);
    }
  }
  if (c > CAP) {  // rare: scan small overflow list
    int nov = min(*ovfc, OVF_MAX);
    for (int i = 0; i < nov; ++i) {
      int e = ovf[i];
      if (dst[e] != n) continue;
      int s = src[e], a = ea[e], bs = batch[s];
      const float* hs = h + (size_t)s * HD;
      const float* vs = vn + (size_t)bs * HD;
      const float* bb = bond + (size_t)a * HD;
      f32x4 hv = *(const f32x4*)(hs + i0);
      f32x4 vv = *(const f32x4*)(vs + i0);
      f32x4 bv = *(const f32x4*)(bb + i0);
#pragma unroll
      for (int q = 0; q < 4; ++q) acc0[q] += fmaxf(hv[q] + vv[q] + bv[q], 0.f);
      if (l2) {
        hv = *(const f32x4*)(hs + i1);
        vv = *(const f32x4*)(vs + i1);
        bv = *(const f32x4*)(bb + i1);
#pragma unroll
        for (int q = 0; q < 4; ++q) acc1[q] += fmaxf(hv[q] + vv[q] + bv[q], 0.f);
      }
    }
  }
  unsigned short* phr = ph + (size_t)n * HDP;
  unsigned short* plr = pl + (size_t)n * HDP;
  short4v h0, l0;
#pragma unroll
  for (int q = 0; q < 4; ++q) {
    short hi = f2bf(acc0[q]); h0[q] = hi; l0[q] = f2bf(acc0[q] - bf2f(hi));
  }
  *(short4v*)(phr + i0) = h0;
  *(short4v*)(plr + i0) = l0;
  if (lane < 12) {  // lanes 0..10 = data; lane 11 = zero pad (shorts 300..303)
    short4v h1, l1;
    if (l2) {
#pragma unroll
      for (int q = 0; q < 4; ++q) {
        short hi = f2bf(acc1[q]); h1[q] = hi; l1[q] = f2bf(acc1[q] - bf2f(hi));
      }
    } else {
#pragma unroll
      for (int q = 0; q < 4; ++q) { h1[q] = 0; l1[q] = 0; }
    }
    *(short4v*)(phr + i1) = h1;
    *(short4v*)(plr + i1) = l1;
  }
}

// ---------- fused BN apply + segment pooling (f32x4, one block per graph) ----------
__global__ __launch_bounds__(64) void k_bn_pool(const float* __restrict__ x,
                                                const float* __restrict__ gw,
                                                const float* __restrict__ bw,
                                                const float* __restrict__ stats,
                                                float invM,
                                                const int* __restrict__ start,
                                                int relu, float* __restrict__ hout,
                                                float* __restrict__ pooled) {
  int grf = blockIdx.x, lane = threadIdx.x;
  int r0 = start[grf], r1 = start[grf + 1];
  const bool l2 = lane < 11;
  const int i0 = lane * 4, i1 = (64 + lane) * 4;
  f32x4 m0, rs0, g0, b0, m1, rs1, g1, b1, acc0, acc1;
  {
    f32x4 s = *(const f32x4*)(stats + i0);
    f32x4 q = *(const f32x4*)(stats + HD + i0);
    g0 = *(const f32x4*)(gw + i0);
    b0 = *(const f32x4*)(bw + i0);
#pragma unroll
    for (int j = 0; j < 4; ++j) {
      float mm = s[j] * invM;
      float vv = q[j] * invM - mm * mm;
      m0[j] = mm; rs0[j] = rsqrtf(vv + 1e-5f);
      acc0[j] = 0.f;
    }
  }
  if (l2) {
    f32x4 s = *(const f32x4*)(stats + i1);
    f32x4 q = *(const f32x4*)(stats + HD + i1);
    g1 = *(const f32x4*)(gw + i1);
    b1 = *(const f32x4*)(bw + i1);
#pragma unroll
    for (int j = 0; j < 4; ++j) {
      float mm = s[j] * invM;
      float vv = q[j] * invM - mm * mm;
      m1[j] = mm; rs1[j] = rsqrtf(vv + 1e-5f);
      acc1[j] = 0.f;
    }
  }
  for (int r = r0; r < r1; ++r) {
    const float* xr = x + (size_t)r * HD;
    f32x4 v = *(const f32x4*)(xr + i0);
#pragma unroll
    for (int j = 0; j < 4; ++j) {
      float val = g0[j] * (v[j] - m0[j]) * rs0[j] + b0[j];
      if (relu) val = fmaxf(val, 0.f);
      v[j] = val;
      acc0[j] += val;
    }
    if (hout) *(f32x4*)(hout + (size_t)r * HD + i0) = v;
    if (l2) {
      f32x4 v2 = *(const f32x4*)(xr + i1);
#pragma unroll
      for (int j = 0; j < 4; ++j) {
        float val = g1[j] * (v2[j] - m1[j]) * rs1[j] + b1[j];
        if (relu) val = fmaxf(val, 0.f);
        v2[j] = val;
        acc1[j] += val;
      }
      if (hout) *(f32x4*)(hout + (size_t)r * HD + i1) = v2;
    }
  }
  float* op = pooled + (size_t)grf * HD;
  *(f32x4*)(op + i0) = acc0;
  if (l2) *(f32x4*)(op + i1) = acc1;
}

// plain BN apply (vt2 -> vn)
__global__ __launch_bounds__(256) void k_bn_apply(const float* __restrict__ x,
                                                  const float* __restrict__ g,
                                                  const float* __restrict__ b,
                                                  const float* __restrict__ stats,
                                                  float invM, int C, int total, int relu,
                                                  float* __restrict__ out) {
  int idx = blockIdx.x * 256 + threadIdx.x;
  if (idx >= total) return;
  int n = idx / C, c = idx - n * C;
  float m = stats[c] * invM;
  float v = stats[C + c] * invM - m * m;
  float val = g[c] * (x[idx] - m) * rsqrtf(v + 1e-5f) + b[c];
  if (relu) val = fmaxf(val, 0.f);
  out[idx] = val;
}

// ---------- init ----------
__global__ __launch_bounds__(256) void k_init_h(const int* __restrict__ x,
                                                const float* __restrict__ emb,
                                                float* __restrict__ h, int nvec) {
  int idx = blockIdx.x * 256 + threadIdx.x;
  if (idx >= nvec) return;
  int n = idx / 75, c4 = idx - n * 75;
  ((float4*)h)[idx] = *(const float4*)(emb + (size_t)x[n] * HD + c4 * 4);
}

__global__ __launch_bounds__(256) void k_init_vn(const float* __restrict__ vn_emb,
                                                 float* __restrict__ vn, int total) {
  int idx = blockIdx.x * 256 + threadIdx.x;
  if (idx >= total) return;
  vn[idx] = vn_emb[idx % HD];
}

extern "C" void kernel_launch(void* const* d_in, const int* in_sizes, int n_in,
                              void* d_out, int out_size, void* d_ws, size_t ws_size,
                              hipStream_t stream) {
  const int N = in_sizes[0];        // 100000
  const int E = in_sizes[2];        // 200000
  const int B = out_size / HD;      // 4096

  const int* x     = (const int*)d_in[0];
  const int* src   = (const int*)d_in[1];
  const int* dst   = src + E;
  const int* ea    = (const int*)d_in[2];
  const int* batch = (const int*)d_in[3];
  const float* atom_emb = (const float*)d_in[5];
  const float* bond_emb = (const float*)d_in[6];
  const float* vn_emb   = (const float*)d_in[7];
  const float* W1   = (const float*)d_in[8];
  const float* b1   = (const float*)d_in[9];
  const float* W2   = (const float*)d_in[10];
  const float* b2   = (const float*)d_in[11];
  const float* bn_g = (const float*)d_in[12];
  const float* bn_b = (const float*)d_in[13];
  const float* vW1  = (const float*)d_in[14];
  const float* vb1  = (const float*)d_in[15];
  const float* vg1  = (const float*)d_in[16];
  const float* vbb1 = (const float*)d_in[17];
  const float* vW2  = (const float*)d_in[18];
  const float* vb2  = (const float*)d_in[19];
  const float* vg2  = (const float*)d_in[20];
  const float* vbb2 = (const float*)d_in[21];

  const size_t NH = (size_t)N * HD;
  const size_t BH = (size_t)B * HD;
  const size_t T1 = (size_t)CT1P * KS1 * 512;  // 204,800 shorts
  const size_t T2 = (size_t)CT2P * KS2 * 512;  // 194,560 shorts
  const size_t NPAD = (size_t)N + 64;          // ph/pl row padding (tail safety)

  // ---- workspace layout ----
  char* base = (char*)d_ws;
  size_t off = 0;
  float* h     = (float*)(base + off); off += NH * 4;
  unsigned short* ph = (unsigned short*)(base + off); off += NPAD * HDP * 2;
  unsigned short* pl = (unsigned short*)(base + off); off += NPAD * HDP * 2;
  float* vn    = (float*)(base + off); off += BH * 4;
  float* vt1   = (float*)(base + off); off += (size_t)B * HD2 * 4;
  float* pool  = (float*)(base + off); off += BH * 4;   // aliased as vt2
  float* vt2   = pool;
  float* stats = (float*)(base + off); off += 12000 * 4;
  int* cnt     = (int*)(base + off); off += (size_t)N * 4;
  int* ovfc    = (int*)(base + off); off += 4;
  int* ovf     = (int*)(base + off); off += (size_t)OVF_MAX * 4;
  int* start   = (int*)(base + off); off += (size_t)(B + 1) * 4;
  int* bucket  = (int*)(base + off); off += (size_t)N * CAP * 4;
  off = (off + 15) & ~(size_t)15;
  short* Ahi   = (short*)(base + off); off += T1 * 2;
  short* Alo   = (short*)(base + off); off += T1 * 2;
  short* Bhi   = (short*)(base + off); off += T2 * 2;
  short* Blo   = (short*)(base + off); off += T2 * 2;
  const size_t need_base = off;
  // optional dedicated VN frag buffers (prep once instead of per layer)
  short* vAhi = (short*)(base + off); off += T1 * 2;
  short* vAlo = (short*)(base + off); off += T1 * 2;
  short* vBhi = (short*)(base + off); off += T2 * 2;
  short* vBlo = (short*)(base + off); off += T2 * 2;
  const size_t need_full = off;
  const bool hoist_vw = (ws_size >= need_full);
  if (ws_size < need_base) {  // diagnostic fallback
    hipMemsetAsync(d_out, 0, (size_t)out_size * sizeof(float), stream);
    return;
  }
  if (!hoist_vw) { vAhi = Ahi; vAlo = Alo; vBhi = Bhi; vBlo = Blo; }

  // stats | cnt | ovfc are contiguous -> single memset
  hipMemsetAsync(stats, 0, 12000 * sizeof(float) + ((size_t)N + 1) * sizeof(int), stream);

  k_scatter<<<(E + 255) / 256, 256, 0, stream>>>(dst, cnt, bucket, ovf, ovfc, E);
  k_bounds<<<(N + 255) / 256, 256, 0, stream>>>(batch, start, N, B);

  const int totBH = (int)BH;
  const int nvNH = (int)NH / 4;
  const int t1 = (int)T1, t2 = (int)T2;
  k_init_h<<<(nvNH + 255) / 256, 256, 0, stream>>>(x, atom_emb, h, nvNH);
  k_init_vn<<<(totBH + 255) / 256, 256, 0, stream>>>(vn_emb, vn, totBH);
  if (hoist_vw) {
    k_prep_wf<<<(t1 + 255) / 256, 256, 0, stream>>>(vW1, vAhi, vAlo, HD, HD2, KS1, t1);
    k_prep_wf<<<(t2 + 255) / 256, 256, 0, stream>>>(vW2, vBhi, vBlo, HD2, HD, KS2, t2);
  }

  for (int i = 0; i < NLAYER; ++i) {
    float* stL  = stats + i * 2400;
    float* stV1 = stL + 2 * HD;
    float* stV2 = stV1 + 2 * HD2;
    const int last = (i == NLAYER - 1);
    float* pool_i = last ? (float*)d_out : pool;

    k_prep_wf<<<(t1 + 255) / 256, 256, 0, stream>>>(
        W1 + (size_t)i * HD * HD2, Ahi, Alo, HD, HD2, KS1, t1);
    k_prep_wf<<<(t2 + 255) / 256, 256, 0, stream>>>(
        W2 + (size_t)i * HD2 * HD, Bhi, Blo, HD2, HD, KS2, t2);

    k_aggr<<<(N * 64 + 255) / 256, 256, 0, stream>>>(
        h, vn, bond_emb, batch, src, dst, ea, bucket, cnt, ovf, ovfc, ph, pl, N);
    k_mlp_mfma<<<(N + 31) / 32, 256, 0, stream>>>(
        ph, pl, Ahi, Alo, b1 + (size_t)i * HD2, Bhi, Blo, b2 + (size_t)i * HD,
        h, stL, N);
    k_bn_pool<<<B, 64, 0, stream>>>(h, bn_g + i * HD, bn_b + i * HD, stL,
                                    1.f / (float)N, start, last ? 0 : 1,
                                    last ? nullptr : h, pool_i);

    if (!last) {
      if (!hoist_vw) {
        k_prep_wf<<<(t1 + 255) / 256, 256, 0, stream>>>(vW1, vAhi, vAlo, HD, HD2, KS1, t1);
      }
      k_gemm_mfma<KS1, 10, false, true><<<B / 32, 512, 0, stream>>>(
          pool, vn, nullptr, nullptr, nullptr, 0.f, vAhi, vAlo, vb1, vt1, stV1, B, HD, HD2);
      if (!hoist_vw) {
        k_prep_wf<<<(t2 + 255) / 256, 256, 0, stream>>>(vW2, vBhi, vBlo, HD2, HD, KS2, t2);
      }
      k_gemm_mfma<KS2, 5, true, true><<<B / 32, 512, 0, stream>>>(
          vt1, nullptr, stV1, vg1, vbb1, 1.f / (float)B, vBhi, vBlo, vb2, vt2, stV2, B, HD2, HD);
      k_bn_apply<<<(totBH + 255) / 256, 256, 0, stream>>>(
          vt2, vg2, vbb2, stV2, 1.f / (float)B, HD, totBH, 1, vn);
    }
  }
}